// Round 7
// baseline (1857.874 us; speedup 1.0000x reference)
//
#include <hip/hip_runtime.h>
#include <math.h>

// Problem constants (C, HID, etc. are structural; N and E taken from in_sizes)
#define CDIM 64
#define NBES 8

#define SQRT3_F     1.7320508075688772f
#define INV_SQRT3_F 0.57735026918962576f
#define INV_SQRT2_F 0.70710678118654752f
#define INV_AVG_NN  0.0625f

__device__ __forceinline__ float silu(float x) {
    return x / (1.0f + expf(-x));
}

// LDS-only barrier: __syncthreads() lowers to "s_waitcnt vmcnt(0) lgkmcnt(0);
// s_barrier", which drains all in-flight global ATOMICS at every phase
// boundary (the round-6 stall). The barriers in k_edge only protect LDS
// buffers, so wait on lgkmcnt only; atomics keep flowing across phases and
// are fenced by dispatch completion.
#define BAR_LGKM()                                          \
    do {                                                    \
        asm volatile("s_waitcnt lgkmcnt(0)" ::: "memory");  \
        __builtin_amdgcn_s_barrier();                       \
    } while (0)

// ---------------------------------------------------------------------------
// h0 init: h0[n,k] = node_embed_W[species[n], k]
__global__ __launch_bounds__(256) void k_init(float* __restrict__ h0,
                                              const int* __restrict__ species,
                                              const float* __restrict__ embedW,
                                              int nnodes) {
    int idx = blockIdx.x * 256 + threadIdx.x;
    if (idx < nnodes * 64) {
        int n = idx >> 6, k = idx & 63;
        h0[idx] = embedW[species[n] * 64 + k];
    }
}

// ---------------------------------------------------------------------------
// lin_up: x0 = h0 @ W0 ; x1[d] = h1[d] @ W1   (h1 stored [N][3][C])
__global__ __launch_bounds__(256) void k_linup(const float* __restrict__ h0,
                                               const float* __restrict__ h1,
                                               const float* __restrict__ W0,
                                               const float* __restrict__ W1,
                                               float* __restrict__ x0,
                                               float* __restrict__ x1,
                                               int nnodes) {
    __shared__ float sh[4][4][64];
    const int w = threadIdx.x >> 6, k = threadIdx.x & 63;
    const int n = blockIdx.x * 4 + w;
    const bool valid = n < nnodes;
    float v0 = valid ? h0[n * 64 + k] : 0.f;
    float v1 = valid ? h1[n * 192 + k] : 0.f;
    float v2 = valid ? h1[n * 192 + 64 + k] : 0.f;
    float v3 = valid ? h1[n * 192 + 128 + k] : 0.f;
    sh[w][0][k] = v0; sh[w][1][k] = v1; sh[w][2][k] = v2; sh[w][3][k] = v3;
    __syncthreads();
    float a0 = 0.f, a1 = 0.f, a2 = 0.f, a3 = 0.f;
    for (int c = 0; c < 64; ++c) {
        float w0 = W0[c * 64 + k], w1 = W1[c * 64 + k];
        a0 = fmaf(sh[w][0][c], w0, a0);
        a1 = fmaf(sh[w][1][c], w1, a1);
        a2 = fmaf(sh[w][2][c], w1, a2);
        a3 = fmaf(sh[w][3][c], w1, a3);
    }
    if (valid) {
        x0[n * 64 + k] = a0;
        x1[n * 192 + k] = a1;
        x1[n * 192 + 64 + k] = a2;
        x1[n * 192 + 128 + k] = a3;
    }
}

// ---------------------------------------------------------------------------
// Edge kernel: 64 edges per 320-thread block.
//
// Round-6 landed the DS-traffic cut (685 -> 602 us). Remaining 360 us is
// stall: (a) allocator sandbagged to 64 VGPR under (320,4) although LDS
// caps residency at 3 blocks/CU anyway -> (320,2) frees ILP registers;
// (b) P3's "#pragma unroll 1" serialized each kt's loads against its FMAs
// -> unroll 2; (c) every __syncthreads drained in-flight atomics
// (vmcnt(0)) at 8 phase boundaries -> BAR_LGKM (lgkmcnt-only).
__global__ __launch_bounds__(320, 2) void k_edge(
    const float* __restrict__ pos, const int* __restrict__ eidx,
    const float* __restrict__ x0, const float* __restrict__ x1,
    const float* __restrict__ W1, const float* __restrict__ W2,
    const float* __restrict__ W3,
    float* __restrict__ M0, float* __restrict__ M1, int nedges) {
    __shared__ __align__(16) float sFEAT[64][8];
    __shared__ float sY1[64][3];
    __shared__ int sSend[64];
    __shared__ int sRecv[64];
    __shared__ __align__(16) float sH2[64 * 68];  // pad 68: b128 rows, banks spread
    __shared__ __align__(16) float sU[5440];      // union: sH1T[64*68] | sTP[5*16*68]

    float* const sH1T = sU;  // [k][edge], stride 68
    float* const sTP = sU;   // [5][16][68]

    const int t = threadIdx.x;
    const int eb = t & 7;          // GEMM: edge sub-index (edges i*8+eb)
    const int cb8 = (t >> 3) * 8;  // GEMM: first owned tpw column (0..312)
    const int wv = t >> 6;         // wave index == path index of owned cols
    const int c0 = cb8 & 63;       // channel offset within path block

    // ---- P0: geometry + radial features (fp64 for accuracy), threads 0..63
    if (t < 64) {
        int e = blockIdx.x * 64 + t;
        int s = 0, r = 0;
        float y0 = 0.f, y1 = 0.f, y2 = 0.f;
        float feats[NBES];
#pragma unroll
        for (int b = 0; b < NBES; ++b) feats[b] = 0.f;
        if (e < nedges) {
            s = eidx[e];
            r = eidx[nedges + e];
            double dx = (double)pos[3 * s + 0] - (double)pos[3 * r + 0];
            double dy = (double)pos[3 * s + 1] - (double)pos[3 * r + 1];
            double dz = (double)pos[3 * s + 2] - (double)pos[3 * r + 2];
            double rr = sqrt(dx * dx + dy * dy + dz * dz);
            if (rr < 1e-6) rr = 1e-6;
            double inv = 1.0 / rr;
            y0 = (float)(1.7320508075688772 * dx * inv);
            y1 = (float)(1.7320508075688772 * dy * inv);
            y2 = (float)(1.7320508075688772 * dz * inv);
            double xx = rr * 0.2;  // r / R_MAX
            double f = 0.0;
            if (xx < 1.0) {
                double x2 = xx * xx, x3 = x2 * xx, x6 = x3 * x3;
                f = 1.0 - 28.0 * x6 + 48.0 * x6 * xx - 21.0 * x6 * x2;
            }
            double pref = 0.63245553203367587 * f * inv;  // sqrt(2/R_MAX)
#pragma unroll
            for (int b = 0; b < NBES; ++b) {
                double arg = (double)(b + 1) * 3.14159265358979324 * rr * 0.2;
                feats[b] = (float)(sin(arg) * pref);
            }
        }
        sSend[t] = s;
        sRecv[t] = r;
        sY1[t][0] = y0; sY1[t][1] = y1; sY1[t][2] = y2;
#pragma unroll
        for (int b = 0; b < NBES; ++b) sFEAT[t][b] = feats[b];
    }
    BAR_LGKM();

    // ---- P1: hid1 = silu(feat @ W1) -> sH1T[k][edge] (transposed, stride 68)
    if (t < 256) {
        const int j = t & 63;
        float w1c[NBES];
#pragma unroll
        for (int b = 0; b < NBES; ++b) w1c[b] = W1[b * 64 + j];
#pragma unroll
        for (int i = 0; i < 16; ++i) {
            int el = wv * 16 + i;
            const float4* fr = (const float4*)(&sFEAT[el][0]);  // broadcast reads
            float4 f0 = fr[0], f1 = fr[1];
            float acc = 0.f;
            acc = fmaf(f0.x, w1c[0], acc);
            acc = fmaf(f0.y, w1c[1], acc);
            acc = fmaf(f0.z, w1c[2], acc);
            acc = fmaf(f0.w, w1c[3], acc);
            acc = fmaf(f1.x, w1c[4], acc);
            acc = fmaf(f1.y, w1c[5], acc);
            acc = fmaf(f1.z, w1c[6], acc);
            acc = fmaf(f1.w, w1c[7], acc);
            sH1T[j * 68 + el] = silu(acc);
        }
    }
    BAR_LGKM();

    // ---- P2: hid2 = silu(hid1 @ W2), 4 edges x 4 cols per thread,
    // A from sH1T (b128), B from global W2 (L1-resident, 16KB).
    if (t < 256) {
        const int eg = t >> 4;         // edge group: edges 4*eg..+4
        const int j4 = (t & 15) * 4;   // col group: cols j4..j4+4
        float a00 = 0.f, a01 = 0.f, a02 = 0.f, a03 = 0.f;
        float a10 = 0.f, a11 = 0.f, a12 = 0.f, a13 = 0.f;
        float a20 = 0.f, a21 = 0.f, a22 = 0.f, a23 = 0.f;
        float a30 = 0.f, a31 = 0.f, a32 = 0.f, a33 = 0.f;
#pragma unroll 4
        for (int k = 0; k < 64; ++k) {
            float4 av = *(const float4*)&sH1T[k * 68 + 4 * eg];
            float4 wv4 = *(const float4*)&W2[k * 64 + j4];
            a00 = fmaf(av.x, wv4.x, a00); a01 = fmaf(av.x, wv4.y, a01);
            a02 = fmaf(av.x, wv4.z, a02); a03 = fmaf(av.x, wv4.w, a03);
            a10 = fmaf(av.y, wv4.x, a10); a11 = fmaf(av.y, wv4.y, a11);
            a12 = fmaf(av.y, wv4.z, a12); a13 = fmaf(av.y, wv4.w, a13);
            a20 = fmaf(av.z, wv4.x, a20); a21 = fmaf(av.z, wv4.y, a21);
            a22 = fmaf(av.z, wv4.z, a22); a23 = fmaf(av.z, wv4.w, a23);
            a30 = fmaf(av.w, wv4.x, a30); a31 = fmaf(av.w, wv4.y, a31);
            a32 = fmaf(av.w, wv4.z, a32); a33 = fmaf(av.w, wv4.w, a33);
        }
        *(float4*)&sH2[(4 * eg + 0) * 68 + j4] =
            make_float4(silu(a00), silu(a01), silu(a02), silu(a03));
        *(float4*)&sH2[(4 * eg + 1) * 68 + j4] =
            make_float4(silu(a10), silu(a11), silu(a12), silu(a13));
        *(float4*)&sH2[(4 * eg + 2) * 68 + j4] =
            make_float4(silu(a20), silu(a21), silu(a22), silu(a23));
        *(float4*)&sH2[(4 * eg + 3) * 68 + j4] =
            make_float4(silu(a30), silu(a31), silu(a32), silu(a33));
    }
    BAR_LGKM();  // sH2 ready; sH1T dead -> union free for sTP

    // ---- P3: barrier-free GEMM
    // acc[i][j] = sum_k sH2[i*8+eb][k] * W3[k][cb8+j]; W3 via VMEM (L2-hot)
    float acc[8][8];
#pragma unroll
    for (int i = 0; i < 8; ++i)
#pragma unroll
        for (int j = 0; j < 8; ++j) acc[i][j] = 0.f;

#pragma unroll 2
    for (int kt = 0; kt < 16; ++kt) {  // K-step 4
        float4 h[8];
#pragma unroll
        for (int i = 0; i < 8; ++i)
            h[i] = *(const float4*)&sH2[(i * 8 + eb) * 68 + kt * 4];
#pragma unroll
        for (int kk = 0; kk < 4; ++kk) {
            const int k = kt * 4 + kk;
            float4 wa = *(const float4*)&W3[k * 320 + cb8];
            float4 wb = *(const float4*)&W3[k * 320 + cb8 + 4];
#pragma unroll
            for (int i = 0; i < 8; ++i) {
                float hv = (kk == 0) ? h[i].x
                         : (kk == 1) ? h[i].y
                         : (kk == 2) ? h[i].z
                                     : h[i].w;
                acc[i][0] = fmaf(hv, wa.x, acc[i][0]);
                acc[i][1] = fmaf(hv, wa.y, acc[i][1]);
                acc[i][2] = fmaf(hv, wa.z, acc[i][2]);
                acc[i][3] = fmaf(hv, wa.w, acc[i][3]);
                acc[i][4] = fmaf(hv, wb.x, acc[i][4]);
                acc[i][5] = fmaf(hv, wb.y, acc[i][5]);
                acc[i][6] = fmaf(hv, wb.z, acc[i][6]);
                acc[i][7] = fmaf(hv, wb.w, acc[i][7]);
            }
        }
    }

    // ---- P4: 4 message phases, 16 edges each. Thread stages acc[2g][*]
    // (edge g*16+eb) and acc[2g+1][*] (edge g*16+8+eb) into sTP[p][el][ch].
#pragma unroll
    for (int g = 0; g < 4; ++g) {
        {
            const int rowA = (wv * 16 + eb) * 68 + c0;
            const int rowB = (wv * 16 + 8 + eb) * 68 + c0;
            *(float4*)&sTP[rowA] =
                make_float4(acc[2 * g][0], acc[2 * g][1], acc[2 * g][2], acc[2 * g][3]);
            *(float4*)&sTP[rowA + 4] =
                make_float4(acc[2 * g][4], acc[2 * g][5], acc[2 * g][6], acc[2 * g][7]);
            *(float4*)&sTP[rowB] =
                make_float4(acc[2 * g + 1][0], acc[2 * g + 1][1], acc[2 * g + 1][2], acc[2 * g + 1][3]);
            *(float4*)&sTP[rowB + 4] =
                make_float4(acc[2 * g + 1][4], acc[2 * g + 1][5], acc[2 * g + 1][6], acc[2 * g + 1][7]);
        }
        BAR_LGKM();  // tpw staged (LDS only; atomics stay in flight)
        // 16 edges x 64 channels = 1024 items over 320 threads
        for (int v = t; v < 1024; v += 320) {
            int i = v >> 6, cc = v & 63;
            int el = g * 16 + i;
            int s = sSend[el], r = sRecv[el];
            float X0 = x0[s * 64 + cc];
            float Xx = x1[s * 192 + cc];
            float Xy = x1[s * 192 + 64 + cc];
            float Xz = x1[s * 192 + 128 + cc];
            float Yx = sY1[el][0], Yy = sY1[el][1], Yz = sY1[el][2];
            float t0 = sTP[(0 * 16 + i) * 68 + cc];
            float t1 = sTP[(1 * 16 + i) * 68 + cc];
            float t2 = sTP[(2 * 16 + i) * 68 + cc];
            float t3 = sTP[(3 * 16 + i) * 68 + cc];
            float t4 = sTP[(4 * 16 + i) * 68 + cc];
            float dotp = Xx * Yx + Xy * Yy + Xz * Yz;
            float m0 = t0 * X0 + t3 * (dotp * INV_SQRT3_F);
            float cx = Xy * Yz - Xz * Yy;
            float cy = Xz * Yx - Xx * Yz;
            float cz = Xx * Yy - Xy * Yx;
            float m1x = t1 * X0 * Yx + t2 * Xx + t4 * (cx * INV_SQRT2_F);
            float m1y = t1 * X0 * Yy + t2 * Xy + t4 * (cy * INV_SQRT2_F);
            float m1z = t1 * X0 * Yz + t2 * Xz + t4 * (cz * INV_SQRT2_F);
            atomicAdd(&M0[r * 64 + cc], m0 * INV_AVG_NN);
            atomicAdd(&M1[r * 192 + cc], m1x * INV_AVG_NN);
            atomicAdd(&M1[r * 192 + 64 + cc], m1y * INV_AVG_NN);
            atomicAdd(&M1[r * 192 + 128 + cc], m1z * INV_AVG_NN);
        }
        BAR_LGKM();  // sTP reads done before next phase overwrites it
    }
}

// ---------------------------------------------------------------------------
// Node update: h = prod_lin( product_basis( lin(M) ) ), in place over M
__global__ __launch_bounds__(256) void k_node(
    float* __restrict__ h0, float* __restrict__ h1,
    const int* __restrict__ species,
    const float* __restrict__ linW0, const float* __restrict__ linW1,
    const float* __restrict__ prodW0, const float* __restrict__ prodW1,
    const float* __restrict__ plinW0, const float* __restrict__ plinW1,
    int nnodes) {
    __shared__ float sh[4][4][64];
    const int w = threadIdx.x >> 6, k = threadIdx.x & 63;
    const int n = blockIdx.x * 4 + w;
    const bool valid = n < nnodes;
    float v0 = valid ? h0[n * 64 + k] : 0.f;
    float v1 = valid ? h1[n * 192 + k] : 0.f;
    float v2 = valid ? h1[n * 192 + 64 + k] : 0.f;
    float v3 = valid ? h1[n * 192 + 128 + k] : 0.f;
    sh[w][0][k] = v0; sh[w][1][k] = v1; sh[w][2][k] = v2; sh[w][3][k] = v3;
    __syncthreads();
    float a0 = 0.f, a1 = 0.f, a2 = 0.f, a3 = 0.f;
    for (int c = 0; c < 64; ++c) {
        float w0 = linW0[c * 64 + k], w1 = linW1[c * 64 + k];
        a0 = fmaf(sh[w][0][c], w0, a0);
        a1 = fmaf(sh[w][1][c], w1, a1);
        a2 = fmaf(sh[w][2][c], w1, a2);
        a3 = fmaf(sh[w][3][c], w1, a3);
    }
    // product basis (elementwise in channel)
    int sp = valid ? species[n] : 0;
    float p00 = prodW0[sp * 192 + k];
    float p01 = prodW0[sp * 192 + 64 + k];
    float p02 = prodW0[sp * 192 + 128 + k];
    float p10 = prodW1[sp * 128 + k];
    float p11 = prodW1[sp * 128 + 64 + k];
    float nsq = a1 * a1 + a2 * a2 + a3 * a3;
    float b0 = p00 * a0 + p01 * (a0 * a0) + p02 * (nsq * INV_SQRT3_F);
    float b1x = p10 * a1 + p11 * (a0 * a1);
    float b1y = p10 * a2 + p11 * (a0 * a2);
    float b1z = p10 * a3 + p11 * (a0 * a3);
    __syncthreads();
    sh[w][0][k] = b0; sh[w][1][k] = b1x; sh[w][2][k] = b1y; sh[w][3][k] = b1z;
    __syncthreads();
    a0 = a1 = a2 = a3 = 0.f;
    for (int c = 0; c < 64; ++c) {
        float w0 = plinW0[c * 64 + k], w1 = plinW1[c * 64 + k];
        a0 = fmaf(sh[w][0][c], w0, a0);
        a1 = fmaf(sh[w][1][c], w1, a1);
        a2 = fmaf(sh[w][2][c], w1, a2);
        a3 = fmaf(sh[w][3][c], w1, a3);
    }
    if (valid) {
        h0[n * 64 + k] = a0;
        h1[n * 192 + k] = a1;
        h1[n * 192 + 64 + k] = a2;
        h1[n * 192 + 128 + k] = a3;
    }
}

// ---------------------------------------------------------------------------
// Output: [N, C, 4] = concat(h0, h1_x, h1_y, h1_z) along last dim
__global__ __launch_bounds__(256) void k_out(const float* __restrict__ h0,
                                             const float* __restrict__ h1,
                                             float4* __restrict__ out,
                                             int nnodes) {
    int idx = blockIdx.x * 256 + threadIdx.x;
    if (idx < nnodes * 64) {
        int n = idx >> 6, c = idx & 63;
        float4 o;
        o.x = h0[idx];
        o.y = h1[n * 192 + c];
        o.z = h1[n * 192 + 64 + c];
        o.w = h1[n * 192 + 128 + c];
        out[idx] = o;
    }
}

// ---------------------------------------------------------------------------
extern "C" void kernel_launch(void* const* d_in, const int* in_sizes, int n_in,
                              void* d_out, int out_size, void* d_ws,
                              size_t ws_size, hipStream_t stream) {
    const float* positions = (const float*)d_in[0];
    const int* species = (const int*)d_in[1];
    const int* eidx = (const int*)d_in[2];
    const float* embedW = (const float*)d_in[3];
    const float* linupW0 = (const float*)d_in[4];
    const float* linupW1 = (const float*)d_in[5];
    const float* mlpW1 = (const float*)d_in[6];
    const float* mlpW2 = (const float*)d_in[7];
    const float* mlpW3 = (const float*)d_in[8];
    const float* linW0 = (const float*)d_in[9];
    const float* linW1 = (const float*)d_in[10];
    const float* prodW0 = (const float*)d_in[11];
    const float* prodW1 = (const float*)d_in[12];
    const float* plinW0 = (const float*)d_in[13];
    const float* plinW1 = (const float*)d_in[14];

    const int nn = in_sizes[0] / 3;   // 25000
    const int ne = in_sizes[2] / 2;   // 400000

    // workspace layout (floats): h0 | h1 | x0 | x1   (M aliases h: h dead
    // once lin_up produced x; node-update reads M row then overwrites it)
    float* h0 = (float*)d_ws;
    float* h1 = h0 + (size_t)nn * 64;
    float* x0 = h1 + (size_t)nn * 192;
    float* x1 = x0 + (size_t)nn * 64;

    const int gridN64 = (nn * 64 + 255) / 256;
    const int gridNode = (nn + 3) / 4;
    const int gridEdge = (ne + 63) / 64;

    hipMemsetAsync(h1, 0, (size_t)nn * 192 * sizeof(float), stream);
    k_init<<<gridN64, 256, 0, stream>>>(h0, species, embedW, nn);

    for (int l = 0; l < 2; ++l) {
        k_linup<<<gridNode, 256, 0, stream>>>(
            h0, h1, linupW0 + l * 4096, linupW1 + l * 4096, x0, x1, nn);
        // zero the scatter accumulators (alias h0/h1)
        hipMemsetAsync(h0, 0, (size_t)nn * 64 * sizeof(float), stream);
        hipMemsetAsync(h1, 0, (size_t)nn * 192 * sizeof(float), stream);
        k_edge<<<gridEdge, 320, 0, stream>>>(
            positions, eidx, x0, x1, mlpW1 + l * 512, mlpW2 + l * 4096,
            mlpW3 + l * 20480, h0, h1, ne);
        k_node<<<gridNode, 256, 0, stream>>>(
            h0, h1, species, linW0 + l * 4096, linW1 + l * 4096,
            prodW0 + l * 768, prodW1 + l * 512, plinW0 + l * 4096,
            plinW1 + l * 4096, nn);
    }
    k_out<<<gridN64, 256, 0, stream>>>(h0, h1, (float4*)d_out, nn);
}

// Round 8
// 1544.467 us; speedup vs baseline: 1.2029x; 1.2029x over previous
//
#include <hip/hip_runtime.h>
#include <math.h>

// Problem constants (C, HID, etc. are structural; N and E taken from in_sizes)
#define CDIM 64
#define NBES 8

#define SQRT3_F     1.7320508075688772f
#define INV_SQRT3_F 0.57735026918962576f
#define INV_SQRT2_F 0.70710678118654752f
#define INV_AVG_NN  0.0625f

__device__ __forceinline__ float silu(float x) {
    return x / (1.0f + expf(-x));
}

// ---------------------------------------------------------------------------
// h0 init: h0[n,k] = node_embed_W[species[n], k]
__global__ __launch_bounds__(256) void k_init(float* __restrict__ h0,
                                              const int* __restrict__ species,
                                              const float* __restrict__ embedW,
                                              int nnodes) {
    int idx = blockIdx.x * 256 + threadIdx.x;
    if (idx < nnodes * 64) {
        int n = idx >> 6, k = idx & 63;
        h0[idx] = embedW[species[n] * 64 + k];
    }
}

// ---------------------------------------------------------------------------
// lin_up: x0 = h0 @ W0 ; x1[d] = h1[d] @ W1   (h1 stored [N][3][C])
__global__ __launch_bounds__(256) void k_linup(const float* __restrict__ h0,
                                               const float* __restrict__ h1,
                                               const float* __restrict__ W0,
                                               const float* __restrict__ W1,
                                               float* __restrict__ x0,
                                               float* __restrict__ x1,
                                               int nnodes) {
    __shared__ float sh[4][4][64];
    const int w = threadIdx.x >> 6, k = threadIdx.x & 63;
    const int n = blockIdx.x * 4 + w;
    const bool valid = n < nnodes;
    float v0 = valid ? h0[n * 64 + k] : 0.f;
    float v1 = valid ? h1[n * 192 + k] : 0.f;
    float v2 = valid ? h1[n * 192 + 64 + k] : 0.f;
    float v3 = valid ? h1[n * 192 + 128 + k] : 0.f;
    sh[w][0][k] = v0; sh[w][1][k] = v1; sh[w][2][k] = v2; sh[w][3][k] = v3;
    __syncthreads();
    float a0 = 0.f, a1 = 0.f, a2 = 0.f, a3 = 0.f;
    for (int c = 0; c < 64; ++c) {
        float w0 = W0[c * 64 + k], w1 = W1[c * 64 + k];
        a0 = fmaf(sh[w][0][c], w0, a0);
        a1 = fmaf(sh[w][1][c], w1, a1);
        a2 = fmaf(sh[w][2][c], w1, a2);
        a3 = fmaf(sh[w][3][c], w1, a3);
    }
    if (valid) {
        x0[n * 64 + k] = a0;
        x1[n * 192 + k] = a1;
        x1[n * 192 + 64 + k] = a2;
        x1[n * 192 + 128 + k] = a3;
    }
}

// ---------------------------------------------------------------------------
// Edge kernel: 64 edges per 320-thread block. EXACTLY the round-6 kernel
// (602 us, best) plus ONE change: sFEAT is overlaid onto the front of sH2.
//
// Occupancy law observed across 8 rounds: VGPR<=64 -> ~23% occupancy,
// VGPR>64 -> ~14.5% (5-wave blocks need robust SIMD packing; the 8-waves/
// SIMD cap at <=64 VGPR provides it). So keep (320,4) / unroll 1 /
// __syncthreads (the r6 config that compiles to 64 VGPR) and instead buy
// occupancy with LDS: sFEAT lives P0->P1 only, sH2 is first written in P2,
// and a barrier already separates them -> overlay saves 2 KB, LDS
// 42496 -> 40448 B <= 40960 -> 4 blocks/CU ceiling (was 3).
__global__ __launch_bounds__(320, 4) void k_edge(
    const float* __restrict__ pos, const int* __restrict__ eidx,
    const float* __restrict__ x0, const float* __restrict__ x1,
    const float* __restrict__ W1, const float* __restrict__ W2,
    const float* __restrict__ W3,
    float* __restrict__ M0, float* __restrict__ M1, int nedges) {
    __shared__ float sY1[64][3];
    __shared__ int sSend[64];
    __shared__ int sRecv[64];
    __shared__ __align__(16) float sH2[64 * 68];  // pad 68: b128 rows, banks spread
    __shared__ __align__(16) float sU[5440];      // union: sH1T[64*68] | sTP[5*16*68]

    float* const sF = sH2;   // overlay: sFEAT[64][8], live P0->P1 only
    float* const sH1T = sU;  // [k][edge], stride 68
    float* const sTP = sU;   // [5][16][68]

    const int t = threadIdx.x;
    const int eb = t & 7;          // GEMM: edge sub-index (edges i*8+eb)
    const int cb8 = (t >> 3) * 8;  // GEMM: first owned tpw column (0..312)
    const int wv = t >> 6;         // wave index == path index of owned cols
    const int c0 = cb8 & 63;       // channel offset within path block

    // ---- P0: geometry + radial features (fp64 for accuracy), threads 0..63
    if (t < 64) {
        int e = blockIdx.x * 64 + t;
        int s = 0, r = 0;
        float y0 = 0.f, y1 = 0.f, y2 = 0.f;
        float feats[NBES];
#pragma unroll
        for (int b = 0; b < NBES; ++b) feats[b] = 0.f;
        if (e < nedges) {
            s = eidx[e];
            r = eidx[nedges + e];
            double dx = (double)pos[3 * s + 0] - (double)pos[3 * r + 0];
            double dy = (double)pos[3 * s + 1] - (double)pos[3 * r + 1];
            double dz = (double)pos[3 * s + 2] - (double)pos[3 * r + 2];
            double rr = sqrt(dx * dx + dy * dy + dz * dz);
            if (rr < 1e-6) rr = 1e-6;
            double inv = 1.0 / rr;
            y0 = (float)(1.7320508075688772 * dx * inv);
            y1 = (float)(1.7320508075688772 * dy * inv);
            y2 = (float)(1.7320508075688772 * dz * inv);
            double xx = rr * 0.2;  // r / R_MAX
            double f = 0.0;
            if (xx < 1.0) {
                double x2 = xx * xx, x3 = x2 * xx, x6 = x3 * x3;
                f = 1.0 - 28.0 * x6 + 48.0 * x6 * xx - 21.0 * x6 * x2;
            }
            double pref = 0.63245553203367587 * f * inv;  // sqrt(2/R_MAX)
#pragma unroll
            for (int b = 0; b < NBES; ++b) {
                double arg = (double)(b + 1) * 3.14159265358979324 * rr * 0.2;
                feats[b] = (float)(sin(arg) * pref);
            }
        }
        sSend[t] = s;
        sRecv[t] = r;
        sY1[t][0] = y0; sY1[t][1] = y1; sY1[t][2] = y2;
#pragma unroll
        for (int b = 0; b < NBES; ++b) sF[t * 8 + b] = feats[b];
    }
    __syncthreads();

    // ---- P1: hid1 = silu(feat @ W1) -> sH1T[k][edge] (transposed, stride 68)
    if (t < 256) {
        const int j = t & 63;
        float w1c[NBES];
#pragma unroll
        for (int b = 0; b < NBES; ++b) w1c[b] = W1[b * 64 + j];
#pragma unroll
        for (int i = 0; i < 16; ++i) {
            int el = wv * 16 + i;
            const float4* fr = (const float4*)(&sF[el * 8]);  // broadcast reads
            float4 f0 = fr[0], f1 = fr[1];
            float acc = 0.f;
            acc = fmaf(f0.x, w1c[0], acc);
            acc = fmaf(f0.y, w1c[1], acc);
            acc = fmaf(f0.z, w1c[2], acc);
            acc = fmaf(f0.w, w1c[3], acc);
            acc = fmaf(f1.x, w1c[4], acc);
            acc = fmaf(f1.y, w1c[5], acc);
            acc = fmaf(f1.z, w1c[6], acc);
            acc = fmaf(f1.w, w1c[7], acc);
            sH1T[j * 68 + el] = silu(acc);
        }
    }
    __syncthreads();  // P1's sF reads complete before P2 overwrites sH2 region

    // ---- P2: hid2 = silu(hid1 @ W2), 4 edges x 4 cols per thread,
    // A from sH1T (b128), B from global W2 (L1-resident, 16KB).
    if (t < 256) {
        const int eg = t >> 4;         // edge group: edges 4*eg..+4
        const int j4 = (t & 15) * 4;   // col group: cols j4..j4+4
        float a00 = 0.f, a01 = 0.f, a02 = 0.f, a03 = 0.f;
        float a10 = 0.f, a11 = 0.f, a12 = 0.f, a13 = 0.f;
        float a20 = 0.f, a21 = 0.f, a22 = 0.f, a23 = 0.f;
        float a30 = 0.f, a31 = 0.f, a32 = 0.f, a33 = 0.f;
#pragma unroll 4
        for (int k = 0; k < 64; ++k) {
            float4 av = *(const float4*)&sH1T[k * 68 + 4 * eg];
            float4 wv4 = *(const float4*)&W2[k * 64 + j4];
            a00 = fmaf(av.x, wv4.x, a00); a01 = fmaf(av.x, wv4.y, a01);
            a02 = fmaf(av.x, wv4.z, a02); a03 = fmaf(av.x, wv4.w, a03);
            a10 = fmaf(av.y, wv4.x, a10); a11 = fmaf(av.y, wv4.y, a11);
            a12 = fmaf(av.y, wv4.z, a12); a13 = fmaf(av.y, wv4.w, a13);
            a20 = fmaf(av.z, wv4.x, a20); a21 = fmaf(av.z, wv4.y, a21);
            a22 = fmaf(av.z, wv4.z, a22); a23 = fmaf(av.z, wv4.w, a23);
            a30 = fmaf(av.w, wv4.x, a30); a31 = fmaf(av.w, wv4.y, a31);
            a32 = fmaf(av.w, wv4.z, a32); a33 = fmaf(av.w, wv4.w, a33);
        }
        *(float4*)&sH2[(4 * eg + 0) * 68 + j4] =
            make_float4(silu(a00), silu(a01), silu(a02), silu(a03));
        *(float4*)&sH2[(4 * eg + 1) * 68 + j4] =
            make_float4(silu(a10), silu(a11), silu(a12), silu(a13));
        *(float4*)&sH2[(4 * eg + 2) * 68 + j4] =
            make_float4(silu(a20), silu(a21), silu(a22), silu(a23));
        *(float4*)&sH2[(4 * eg + 3) * 68 + j4] =
            make_float4(silu(a30), silu(a31), silu(a32), silu(a33));
    }
    __syncthreads();  // sH2 ready; sH1T dead -> union free for sTP

    // ---- P3: barrier-free GEMM
    // acc[i][j] = sum_k sH2[i*8+eb][k] * W3[k][cb8+j]; W3 via VMEM (L2-hot)
    float acc[8][8];
#pragma unroll
    for (int i = 0; i < 8; ++i)
#pragma unroll
        for (int j = 0; j < 8; ++j) acc[i][j] = 0.f;

#pragma unroll 1
    for (int kt = 0; kt < 16; ++kt) {  // K-step 4
        float4 h[8];
#pragma unroll
        for (int i = 0; i < 8; ++i)
            h[i] = *(const float4*)&sH2[(i * 8 + eb) * 68 + kt * 4];
#pragma unroll
        for (int kk = 0; kk < 4; ++kk) {
            const int k = kt * 4 + kk;
            float4 wa = *(const float4*)&W3[k * 320 + cb8];
            float4 wb = *(const float4*)&W3[k * 320 + cb8 + 4];
#pragma unroll
            for (int i = 0; i < 8; ++i) {
                float hv = (kk == 0) ? h[i].x
                         : (kk == 1) ? h[i].y
                         : (kk == 2) ? h[i].z
                                     : h[i].w;
                acc[i][0] = fmaf(hv, wa.x, acc[i][0]);
                acc[i][1] = fmaf(hv, wa.y, acc[i][1]);
                acc[i][2] = fmaf(hv, wa.z, acc[i][2]);
                acc[i][3] = fmaf(hv, wa.w, acc[i][3]);
                acc[i][4] = fmaf(hv, wb.x, acc[i][4]);
                acc[i][5] = fmaf(hv, wb.y, acc[i][5]);
                acc[i][6] = fmaf(hv, wb.z, acc[i][6]);
                acc[i][7] = fmaf(hv, wb.w, acc[i][7]);
            }
        }
    }

    // ---- P4: 4 message phases, 16 edges each. Thread stages acc[2g][*]
    // (edge g*16+eb) and acc[2g+1][*] (edge g*16+8+eb) into sTP[p][el][ch].
#pragma unroll
    for (int g = 0; g < 4; ++g) {
        {
            const int rowA = (wv * 16 + eb) * 68 + c0;
            const int rowB = (wv * 16 + 8 + eb) * 68 + c0;
            *(float4*)&sTP[rowA] =
                make_float4(acc[2 * g][0], acc[2 * g][1], acc[2 * g][2], acc[2 * g][3]);
            *(float4*)&sTP[rowA + 4] =
                make_float4(acc[2 * g][4], acc[2 * g][5], acc[2 * g][6], acc[2 * g][7]);
            *(float4*)&sTP[rowB] =
                make_float4(acc[2 * g + 1][0], acc[2 * g + 1][1], acc[2 * g + 1][2], acc[2 * g + 1][3]);
            *(float4*)&sTP[rowB + 4] =
                make_float4(acc[2 * g + 1][4], acc[2 * g + 1][5], acc[2 * g + 1][6], acc[2 * g + 1][7]);
        }
        __syncthreads();  // tpw staged
        // 16 edges x 64 channels = 1024 items over 320 threads
        for (int v = t; v < 1024; v += 320) {
            int i = v >> 6, cc = v & 63;
            int el = g * 16 + i;
            int s = sSend[el], r = sRecv[el];
            float X0 = x0[s * 64 + cc];
            float Xx = x1[s * 192 + cc];
            float Xy = x1[s * 192 + 64 + cc];
            float Xz = x1[s * 192 + 128 + cc];
            float Yx = sY1[el][0], Yy = sY1[el][1], Yz = sY1[el][2];
            float t0 = sTP[(0 * 16 + i) * 68 + cc];
            float t1 = sTP[(1 * 16 + i) * 68 + cc];
            float t2 = sTP[(2 * 16 + i) * 68 + cc];
            float t3 = sTP[(3 * 16 + i) * 68 + cc];
            float t4 = sTP[(4 * 16 + i) * 68 + cc];
            float dotp = Xx * Yx + Xy * Yy + Xz * Yz;
            float m0 = t0 * X0 + t3 * (dotp * INV_SQRT3_F);
            float cx = Xy * Yz - Xz * Yy;
            float cy = Xz * Yx - Xx * Yz;
            float cz = Xx * Yy - Xy * Yx;
            float m1x = t1 * X0 * Yx + t2 * Xx + t4 * (cx * INV_SQRT2_F);
            float m1y = t1 * X0 * Yy + t2 * Xy + t4 * (cy * INV_SQRT2_F);
            float m1z = t1 * X0 * Yz + t2 * Xz + t4 * (cz * INV_SQRT2_F);
            atomicAdd(&M0[r * 64 + cc], m0 * INV_AVG_NN);
            atomicAdd(&M1[r * 192 + cc], m1x * INV_AVG_NN);
            atomicAdd(&M1[r * 192 + 64 + cc], m1y * INV_AVG_NN);
            atomicAdd(&M1[r * 192 + 128 + cc], m1z * INV_AVG_NN);
        }
        __syncthreads();  // sTP reads done before next phase overwrites it
    }
}

// ---------------------------------------------------------------------------
// Node update: h = prod_lin( product_basis( lin(M) ) ), in place over M
__global__ __launch_bounds__(256) void k_node(
    float* __restrict__ h0, float* __restrict__ h1,
    const int* __restrict__ species,
    const float* __restrict__ linW0, const float* __restrict__ linW1,
    const float* __restrict__ prodW0, const float* __restrict__ prodW1,
    const float* __restrict__ plinW0, const float* __restrict__ plinW1,
    int nnodes) {
    __shared__ float sh[4][4][64];
    const int w = threadIdx.x >> 6, k = threadIdx.x & 63;
    const int n = blockIdx.x * 4 + w;
    const bool valid = n < nnodes;
    float v0 = valid ? h0[n * 64 + k] : 0.f;
    float v1 = valid ? h1[n * 192 + k] : 0.f;
    float v2 = valid ? h1[n * 192 + 64 + k] : 0.f;
    float v3 = valid ? h1[n * 192 + 128 + k] : 0.f;
    sh[w][0][k] = v0; sh[w][1][k] = v1; sh[w][2][k] = v2; sh[w][3][k] = v3;
    __syncthreads();
    float a0 = 0.f, a1 = 0.f, a2 = 0.f, a3 = 0.f;
    for (int c = 0; c < 64; ++c) {
        float w0 = linW0[c * 64 + k], w1 = linW1[c * 64 + k];
        a0 = fmaf(sh[w][0][c], w0, a0);
        a1 = fmaf(sh[w][1][c], w1, a1);
        a2 = fmaf(sh[w][2][c], w1, a2);
        a3 = fmaf(sh[w][3][c], w1, a3);
    }
    // product basis (elementwise in channel)
    int sp = valid ? species[n] : 0;
    float p00 = prodW0[sp * 192 + k];
    float p01 = prodW0[sp * 192 + 64 + k];
    float p02 = prodW0[sp * 192 + 128 + k];
    float p10 = prodW1[sp * 128 + k];
    float p11 = prodW1[sp * 128 + 64 + k];
    float nsq = a1 * a1 + a2 * a2 + a3 * a3;
    float b0 = p00 * a0 + p01 * (a0 * a0) + p02 * (nsq * INV_SQRT3_F);
    float b1x = p10 * a1 + p11 * (a0 * a1);
    float b1y = p10 * a2 + p11 * (a0 * a2);
    float b1z = p10 * a3 + p11 * (a0 * a3);
    __syncthreads();
    sh[w][0][k] = b0; sh[w][1][k] = b1x; sh[w][2][k] = b1y; sh[w][3][k] = b1z;
    __syncthreads();
    a0 = a1 = a2 = a3 = 0.f;
    for (int c = 0; c < 64; ++c) {
        float w0 = plinW0[c * 64 + k], w1 = plinW1[c * 64 + k];
        a0 = fmaf(sh[w][0][c], w0, a0);
        a1 = fmaf(sh[w][1][c], w1, a1);
        a2 = fmaf(sh[w][2][c], w1, a2);
        a3 = fmaf(sh[w][3][c], w1, a3);
    }
    if (valid) {
        h0[n * 64 + k] = a0;
        h1[n * 192 + k] = a1;
        h1[n * 192 + 64 + k] = a2;
        h1[n * 192 + 128 + k] = a3;
    }
}

// ---------------------------------------------------------------------------
// Output: [N, C, 4] = concat(h0, h1_x, h1_y, h1_z) along last dim
__global__ __launch_bounds__(256) void k_out(const float* __restrict__ h0,
                                             const float* __restrict__ h1,
                                             float4* __restrict__ out,
                                             int nnodes) {
    int idx = blockIdx.x * 256 + threadIdx.x;
    if (idx < nnodes * 64) {
        int n = idx >> 6, c = idx & 63;
        float4 o;
        o.x = h0[idx];
        o.y = h1[n * 192 + c];
        o.z = h1[n * 192 + 64 + c];
        o.w = h1[n * 192 + 128 + c];
        out[idx] = o;
    }
}

// ---------------------------------------------------------------------------
extern "C" void kernel_launch(void* const* d_in, const int* in_sizes, int n_in,
                              void* d_out, int out_size, void* d_ws,
                              size_t ws_size, hipStream_t stream) {
    const float* positions = (const float*)d_in[0];
    const int* species = (const int*)d_in[1];
    const int* eidx = (const int*)d_in[2];
    const float* embedW = (const float*)d_in[3];
    const float* linupW0 = (const float*)d_in[4];
    const float* linupW1 = (const float*)d_in[5];
    const float* mlpW1 = (const float*)d_in[6];
    const float* mlpW2 = (const float*)d_in[7];
    const float* mlpW3 = (const float*)d_in[8];
    const float* linW0 = (const float*)d_in[9];
    const float* linW1 = (const float*)d_in[10];
    const float* prodW0 = (const float*)d_in[11];
    const float* prodW1 = (const float*)d_in[12];
    const float* plinW0 = (const float*)d_in[13];
    const float* plinW1 = (const float*)d_in[14];

    const int nn = in_sizes[0] / 3;   // 25000
    const int ne = in_sizes[2] / 2;   // 400000

    // workspace layout (floats): h0 | h1 | x0 | x1   (M aliases h: h dead
    // once lin_up produced x; node-update reads M row then overwrites it)
    float* h0 = (float*)d_ws;
    float* h1 = h0 + (size_t)nn * 64;
    float* x0 = h1 + (size_t)nn * 192;
    float* x1 = x0 + (size_t)nn * 64;

    const int gridN64 = (nn * 64 + 255) / 256;
    const int gridNode = (nn + 3) / 4;
    const int gridEdge = (ne + 63) / 64;

    hipMemsetAsync(h1, 0, (size_t)nn * 192 * sizeof(float), stream);
    k_init<<<gridN64, 256, 0, stream>>>(h0, species, embedW, nn);

    for (int l = 0; l < 2; ++l) {
        k_linup<<<gridNode, 256, 0, stream>>>(
            h0, h1, linupW0 + l * 4096, linupW1 + l * 4096, x0, x1, nn);
        // zero the scatter accumulators (alias h0/h1)
        hipMemsetAsync(h0, 0, (size_t)nn * 64 * sizeof(float), stream);
        hipMemsetAsync(h1, 0, (size_t)nn * 192 * sizeof(float), stream);
        k_edge<<<gridEdge, 320, 0, stream>>>(
            positions, eidx, x0, x1, mlpW1 + l * 512, mlpW2 + l * 4096,
            mlpW3 + l * 20480, h0, h1, ne);
        k_node<<<gridNode, 256, 0, stream>>>(
            h0, h1, species, linW0 + l * 4096, linW1 + l * 4096,
            prodW0 + l * 768, prodW1 + l * 512, plinW0 + l * 4096,
            plinW1 + l * 4096, nn);
    }
    k_out<<<gridN64, 256, 0, stream>>>(h0, h1, (float4*)d_out, nn);
}

// Round 9
// 1371.855 us; speedup vs baseline: 1.3543x; 1.1258x over previous
//
#include <hip/hip_runtime.h>
#include <math.h>

// Problem constants (C, HID, etc. are structural; N and E taken from in_sizes)
#define CDIM 64
#define NBES 8

#define SQRT3_F     1.7320508075688772f
#define INV_SQRT3_F 0.57735026918962576f
#define INV_SQRT2_F 0.70710678118654752f
#define INV_AVG_NN  0.0625f

__device__ __forceinline__ float silu(float x) {
    return x / (1.0f + expf(-x));
}

// ---------------------------------------------------------------------------
// init: h0[n,k] = node_embed_W[species[n], k]; h1 = 0 (replaces the h1 memset)
__global__ __launch_bounds__(256) void k_init(float* __restrict__ h0,
                                              float* __restrict__ h1,
                                              const int* __restrict__ species,
                                              const float* __restrict__ embedW,
                                              int nnodes) {
    int idx = blockIdx.x * 256 + threadIdx.x;
    int n64 = nnodes * 64;
    if (idx < n64) {
        int n = idx >> 6, k = idx & 63;
        h0[idx] = embedW[species[n] * 64 + k];
    } else if (idx < nnodes * 256) {
        h1[idx - n64] = 0.f;
    }
}

// ---------------------------------------------------------------------------
// lin_up: x0 = h0 @ W0 ; x1[d] = h1[d] @ W1   (h1 stored [N][3][C])
// Also ZEROES h0/h1 in place after consuming them (h aliases the scatter
// accumulators M0/M1 that k_edge atomically accumulates into) — this
// replaces the two per-layer hipMemsetAsync dispatches. Each row is read
// and zeroed by exactly one thread, and the zero-store targets the same
// address as the load, so ordering is guaranteed.
__global__ __launch_bounds__(256) void k_linup(float* __restrict__ h0,
                                               float* __restrict__ h1,
                                               const float* __restrict__ W0,
                                               const float* __restrict__ W1,
                                               float* __restrict__ x0,
                                               float* __restrict__ x1,
                                               int nnodes) {
    __shared__ float sh[4][4][64];
    const int w = threadIdx.x >> 6, k = threadIdx.x & 63;
    const int n = blockIdx.x * 4 + w;
    const bool valid = n < nnodes;
    float v0 = valid ? h0[n * 64 + k] : 0.f;
    float v1 = valid ? h1[n * 192 + k] : 0.f;
    float v2 = valid ? h1[n * 192 + 64 + k] : 0.f;
    float v3 = valid ? h1[n * 192 + 128 + k] : 0.f;
    sh[w][0][k] = v0; sh[w][1][k] = v1; sh[w][2][k] = v2; sh[w][3][k] = v3;
    if (valid) {  // zero the scatter accumulators (fused memset)
        h0[n * 64 + k] = 0.f;
        h1[n * 192 + k] = 0.f;
        h1[n * 192 + 64 + k] = 0.f;
        h1[n * 192 + 128 + k] = 0.f;
    }
    __syncthreads();
    float a0 = 0.f, a1 = 0.f, a2 = 0.f, a3 = 0.f;
    for (int c = 0; c < 64; ++c) {
        float w0 = W0[c * 64 + k], w1 = W1[c * 64 + k];
        a0 = fmaf(sh[w][0][c], w0, a0);
        a1 = fmaf(sh[w][1][c], w1, a1);
        a2 = fmaf(sh[w][2][c], w1, a2);
        a3 = fmaf(sh[w][3][c], w1, a3);
    }
    if (valid) {
        x0[n * 64 + k] = a0;
        x1[n * 192 + k] = a1;
        x1[n * 192 + 64 + k] = a2;
        x1[n * 192 + 128 + k] = a3;
    }
}

// ---------------------------------------------------------------------------
// Edge kernel: 64 edges per 320-thread block. BYTE-IDENTICAL to the round-6
// version (602 us, the session best). Nine rounds of evidence: this
// kernel's schedule quality is codegen-sensitive (r7/r8 perturbations cost
// 95-240 us at identical counters), so it is frozen. Structure:
// P0 geometry -> P1 hid1 (sH1T transposed) -> P2 hid2 (4x4 reg tile, W2
// from global) -> P3 barrier-free 8x8 GEMM (W3 from global, L2-hot) ->
// P4 4 message phases with atomic scatter.
__global__ __launch_bounds__(320, 4) void k_edge(
    const float* __restrict__ pos, const int* __restrict__ eidx,
    const float* __restrict__ x0, const float* __restrict__ x1,
    const float* __restrict__ W1, const float* __restrict__ W2,
    const float* __restrict__ W3,
    float* __restrict__ M0, float* __restrict__ M1, int nedges) {
    __shared__ __align__(16) float sFEAT[64][8];
    __shared__ float sY1[64][3];
    __shared__ int sSend[64];
    __shared__ int sRecv[64];
    __shared__ __align__(16) float sH2[64 * 68];  // pad 68: b128 rows, banks spread
    __shared__ __align__(16) float sU[5440];      // union: sH1T[64*68] | sTP[5*16*68]

    float* const sH1T = sU;  // [k][edge], stride 68
    float* const sTP = sU;   // [5][16][68]

    const int t = threadIdx.x;
    const int eb = t & 7;          // GEMM: edge sub-index (edges i*8+eb)
    const int cb8 = (t >> 3) * 8;  // GEMM: first owned tpw column (0..312)
    const int wv = t >> 6;         // wave index == path index of owned cols
    const int c0 = cb8 & 63;       // channel offset within path block

    // ---- P0: geometry + radial features (fp64 for accuracy), threads 0..63
    if (t < 64) {
        int e = blockIdx.x * 64 + t;
        int s = 0, r = 0;
        float y0 = 0.f, y1 = 0.f, y2 = 0.f;
        float feats[NBES];
#pragma unroll
        for (int b = 0; b < NBES; ++b) feats[b] = 0.f;
        if (e < nedges) {
            s = eidx[e];
            r = eidx[nedges + e];
            double dx = (double)pos[3 * s + 0] - (double)pos[3 * r + 0];
            double dy = (double)pos[3 * s + 1] - (double)pos[3 * r + 1];
            double dz = (double)pos[3 * s + 2] - (double)pos[3 * r + 2];
            double rr = sqrt(dx * dx + dy * dy + dz * dz);
            if (rr < 1e-6) rr = 1e-6;
            double inv = 1.0 / rr;
            y0 = (float)(1.7320508075688772 * dx * inv);
            y1 = (float)(1.7320508075688772 * dy * inv);
            y2 = (float)(1.7320508075688772 * dz * inv);
            double xx = rr * 0.2;  // r / R_MAX
            double f = 0.0;
            if (xx < 1.0) {
                double x2 = xx * xx, x3 = x2 * xx, x6 = x3 * x3;
                f = 1.0 - 28.0 * x6 + 48.0 * x6 * xx - 21.0 * x6 * x2;
            }
            double pref = 0.63245553203367587 * f * inv;  // sqrt(2/R_MAX)
#pragma unroll
            for (int b = 0; b < NBES; ++b) {
                double arg = (double)(b + 1) * 3.14159265358979324 * rr * 0.2;
                feats[b] = (float)(sin(arg) * pref);
            }
        }
        sSend[t] = s;
        sRecv[t] = r;
        sY1[t][0] = y0; sY1[t][1] = y1; sY1[t][2] = y2;
#pragma unroll
        for (int b = 0; b < NBES; ++b) sFEAT[t][b] = feats[b];
    }
    __syncthreads();

    // ---- P1: hid1 = silu(feat @ W1) -> sH1T[k][edge] (transposed, stride 68)
    if (t < 256) {
        const int j = t & 63;
        float w1c[NBES];
#pragma unroll
        for (int b = 0; b < NBES; ++b) w1c[b] = W1[b * 64 + j];
#pragma unroll
        for (int i = 0; i < 16; ++i) {
            int el = wv * 16 + i;
            const float4* fr = (const float4*)(&sFEAT[el][0]);  // broadcast reads
            float4 f0 = fr[0], f1 = fr[1];
            float acc = 0.f;
            acc = fmaf(f0.x, w1c[0], acc);
            acc = fmaf(f0.y, w1c[1], acc);
            acc = fmaf(f0.z, w1c[2], acc);
            acc = fmaf(f0.w, w1c[3], acc);
            acc = fmaf(f1.x, w1c[4], acc);
            acc = fmaf(f1.y, w1c[5], acc);
            acc = fmaf(f1.z, w1c[6], acc);
            acc = fmaf(f1.w, w1c[7], acc);
            sH1T[j * 68 + el] = silu(acc);
        }
    }
    __syncthreads();

    // ---- P2: hid2 = silu(hid1 @ W2), 4 edges x 4 cols per thread,
    // A from sH1T (b128), B from global W2 (L1-resident, 16KB).
    if (t < 256) {
        const int eg = t >> 4;         // edge group: edges 4*eg..+4
        const int j4 = (t & 15) * 4;   // col group: cols j4..j4+4
        float a00 = 0.f, a01 = 0.f, a02 = 0.f, a03 = 0.f;
        float a10 = 0.f, a11 = 0.f, a12 = 0.f, a13 = 0.f;
        float a20 = 0.f, a21 = 0.f, a22 = 0.f, a23 = 0.f;
        float a30 = 0.f, a31 = 0.f, a32 = 0.f, a33 = 0.f;
#pragma unroll 4
        for (int k = 0; k < 64; ++k) {
            float4 av = *(const float4*)&sH1T[k * 68 + 4 * eg];
            float4 wv4 = *(const float4*)&W2[k * 64 + j4];
            a00 = fmaf(av.x, wv4.x, a00); a01 = fmaf(av.x, wv4.y, a01);
            a02 = fmaf(av.x, wv4.z, a02); a03 = fmaf(av.x, wv4.w, a03);
            a10 = fmaf(av.y, wv4.x, a10); a11 = fmaf(av.y, wv4.y, a11);
            a12 = fmaf(av.y, wv4.z, a12); a13 = fmaf(av.y, wv4.w, a13);
            a20 = fmaf(av.z, wv4.x, a20); a21 = fmaf(av.z, wv4.y, a21);
            a22 = fmaf(av.z, wv4.z, a22); a23 = fmaf(av.z, wv4.w, a23);
            a30 = fmaf(av.w, wv4.x, a30); a31 = fmaf(av.w, wv4.y, a31);
            a32 = fmaf(av.w, wv4.z, a32); a33 = fmaf(av.w, wv4.w, a33);
        }
        *(float4*)&sH2[(4 * eg + 0) * 68 + j4] =
            make_float4(silu(a00), silu(a01), silu(a02), silu(a03));
        *(float4*)&sH2[(4 * eg + 1) * 68 + j4] =
            make_float4(silu(a10), silu(a11), silu(a12), silu(a13));
        *(float4*)&sH2[(4 * eg + 2) * 68 + j4] =
            make_float4(silu(a20), silu(a21), silu(a22), silu(a23));
        *(float4*)&sH2[(4 * eg + 3) * 68 + j4] =
            make_float4(silu(a30), silu(a31), silu(a32), silu(a33));
    }
    __syncthreads();  // sH2 ready; sH1T dead -> union free for sTP

    // ---- P3: barrier-free GEMM
    // acc[i][j] = sum_k sH2[i*8+eb][k] * W3[k][cb8+j]; W3 via VMEM (L2-hot)
    float acc[8][8];
#pragma unroll
    for (int i = 0; i < 8; ++i)
#pragma unroll
        for (int j = 0; j < 8; ++j) acc[i][j] = 0.f;

#pragma unroll 1
    for (int kt = 0; kt < 16; ++kt) {  // K-step 4
        float4 h[8];
#pragma unroll
        for (int i = 0; i < 8; ++i)
            h[i] = *(const float4*)&sH2[(i * 8 + eb) * 68 + kt * 4];
#pragma unroll
        for (int kk = 0; kk < 4; ++kk) {
            const int k = kt * 4 + kk;
            float4 wa = *(const float4*)&W3[k * 320 + cb8];
            float4 wb = *(const float4*)&W3[k * 320 + cb8 + 4];
#pragma unroll
            for (int i = 0; i < 8; ++i) {
                float hv = (kk == 0) ? h[i].x
                         : (kk == 1) ? h[i].y
                         : (kk == 2) ? h[i].z
                                     : h[i].w;
                acc[i][0] = fmaf(hv, wa.x, acc[i][0]);
                acc[i][1] = fmaf(hv, wa.y, acc[i][1]);
                acc[i][2] = fmaf(hv, wa.z, acc[i][2]);
                acc[i][3] = fmaf(hv, wa.w, acc[i][3]);
                acc[i][4] = fmaf(hv, wb.x, acc[i][4]);
                acc[i][5] = fmaf(hv, wb.y, acc[i][5]);
                acc[i][6] = fmaf(hv, wb.z, acc[i][6]);
                acc[i][7] = fmaf(hv, wb.w, acc[i][7]);
            }
        }
    }

    // ---- P4: 4 message phases, 16 edges each. Thread stages acc[2g][*]
    // (edge g*16+eb) and acc[2g+1][*] (edge g*16+8+eb) into sTP[p][el][ch].
#pragma unroll
    for (int g = 0; g < 4; ++g) {
        {
            const int rowA = (wv * 16 + eb) * 68 + c0;
            const int rowB = (wv * 16 + 8 + eb) * 68 + c0;
            *(float4*)&sTP[rowA] =
                make_float4(acc[2 * g][0], acc[2 * g][1], acc[2 * g][2], acc[2 * g][3]);
            *(float4*)&sTP[rowA + 4] =
                make_float4(acc[2 * g][4], acc[2 * g][5], acc[2 * g][6], acc[2 * g][7]);
            *(float4*)&sTP[rowB] =
                make_float4(acc[2 * g + 1][0], acc[2 * g + 1][1], acc[2 * g + 1][2], acc[2 * g + 1][3]);
            *(float4*)&sTP[rowB + 4] =
                make_float4(acc[2 * g + 1][4], acc[2 * g + 1][5], acc[2 * g + 1][6], acc[2 * g + 1][7]);
        }
        __syncthreads();  // tpw staged
        // 16 edges x 64 channels = 1024 items over 320 threads
        for (int v = t; v < 1024; v += 320) {
            int i = v >> 6, cc = v & 63;
            int el = g * 16 + i;
            int s = sSend[el], r = sRecv[el];
            float X0 = x0[s * 64 + cc];
            float Xx = x1[s * 192 + cc];
            float Xy = x1[s * 192 + 64 + cc];
            float Xz = x1[s * 192 + 128 + cc];
            float Yx = sY1[el][0], Yy = sY1[el][1], Yz = sY1[el][2];
            float t0 = sTP[(0 * 16 + i) * 68 + cc];
            float t1 = sTP[(1 * 16 + i) * 68 + cc];
            float t2 = sTP[(2 * 16 + i) * 68 + cc];
            float t3 = sTP[(3 * 16 + i) * 68 + cc];
            float t4 = sTP[(4 * 16 + i) * 68 + cc];
            float dotp = Xx * Yx + Xy * Yy + Xz * Yz;
            float m0 = t0 * X0 + t3 * (dotp * INV_SQRT3_F);
            float cx = Xy * Yz - Xz * Yy;
            float cy = Xz * Yx - Xx * Yz;
            float cz = Xx * Yy - Xy * Yx;
            float m1x = t1 * X0 * Yx + t2 * Xx + t4 * (cx * INV_SQRT2_F);
            float m1y = t1 * X0 * Yy + t2 * Xy + t4 * (cy * INV_SQRT2_F);
            float m1z = t1 * X0 * Yz + t2 * Xz + t4 * (cz * INV_SQRT2_F);
            atomicAdd(&M0[r * 64 + cc], m0 * INV_AVG_NN);
            atomicAdd(&M1[r * 192 + cc], m1x * INV_AVG_NN);
            atomicAdd(&M1[r * 192 + 64 + cc], m1y * INV_AVG_NN);
            atomicAdd(&M1[r * 192 + 128 + cc], m1z * INV_AVG_NN);
        }
        __syncthreads();  // sTP reads done before next phase overwrites it
    }
}

// ---------------------------------------------------------------------------
// Node update: h = prod_lin( product_basis( lin(M) ) ), in place over M
__global__ __launch_bounds__(256) void k_node(
    float* __restrict__ h0, float* __restrict__ h1,
    const int* __restrict__ species,
    const float* __restrict__ linW0, const float* __restrict__ linW1,
    const float* __restrict__ prodW0, const float* __restrict__ prodW1,
    const float* __restrict__ plinW0, const float* __restrict__ plinW1,
    int nnodes) {
    __shared__ float sh[4][4][64];
    const int w = threadIdx.x >> 6, k = threadIdx.x & 63;
    const int n = blockIdx.x * 4 + w;
    const bool valid = n < nnodes;
    float v0 = valid ? h0[n * 64 + k] : 0.f;
    float v1 = valid ? h1[n * 192 + k] : 0.f;
    float v2 = valid ? h1[n * 192 + 64 + k] : 0.f;
    float v3 = valid ? h1[n * 192 + 128 + k] : 0.f;
    sh[w][0][k] = v0; sh[w][1][k] = v1; sh[w][2][k] = v2; sh[w][3][k] = v3;
    __syncthreads();
    float a0 = 0.f, a1 = 0.f, a2 = 0.f, a3 = 0.f;
    for (int c = 0; c < 64; ++c) {
        float w0 = linW0[c * 64 + k], w1 = linW1[c * 64 + k];
        a0 = fmaf(sh[w][0][c], w0, a0);
        a1 = fmaf(sh[w][1][c], w1, a1);
        a2 = fmaf(sh[w][2][c], w1, a2);
        a3 = fmaf(sh[w][3][c], w1, a3);
    }
    // product basis (elementwise in channel)
    int sp = valid ? species[n] : 0;
    float p00 = prodW0[sp * 192 + k];
    float p01 = prodW0[sp * 192 + 64 + k];
    float p02 = prodW0[sp * 192 + 128 + k];
    float p10 = prodW1[sp * 128 + k];
    float p11 = prodW1[sp * 128 + 64 + k];
    float nsq = a1 * a1 + a2 * a2 + a3 * a3;
    float b0 = p00 * a0 + p01 * (a0 * a0) + p02 * (nsq * INV_SQRT3_F);
    float b1x = p10 * a1 + p11 * (a0 * a1);
    float b1y = p10 * a2 + p11 * (a0 * a2);
    float b1z = p10 * a3 + p11 * (a0 * a3);
    __syncthreads();
    sh[w][0][k] = b0; sh[w][1][k] = b1x; sh[w][2][k] = b1y; sh[w][3][k] = b1z;
    __syncthreads();
    a0 = a1 = a2 = a3 = 0.f;
    for (int c = 0; c < 64; ++c) {
        float w0 = plinW0[c * 64 + k], w1 = plinW1[c * 64 + k];
        a0 = fmaf(sh[w][0][c], w0, a0);
        a1 = fmaf(sh[w][1][c], w1, a1);
        a2 = fmaf(sh[w][2][c], w1, a2);
        a3 = fmaf(sh[w][3][c], w1, a3);
    }
    if (valid) {
        h0[n * 64 + k] = a0;
        h1[n * 192 + k] = a1;
        h1[n * 192 + 64 + k] = a2;
        h1[n * 192 + 128 + k] = a3;
    }
}

// ---------------------------------------------------------------------------
// Output: [N, C, 4] = concat(h0, h1_x, h1_y, h1_z) along last dim
__global__ __launch_bounds__(256) void k_out(const float* __restrict__ h0,
                                             const float* __restrict__ h1,
                                             float4* __restrict__ out,
                                             int nnodes) {
    int idx = blockIdx.x * 256 + threadIdx.x;
    if (idx < nnodes * 64) {
        int n = idx >> 6, c = idx & 63;
        float4 o;
        o.x = h0[idx];
        o.y = h1[n * 192 + c];
        o.z = h1[n * 192 + 64 + c];
        o.w = h1[n * 192 + 128 + c];
        out[idx] = o;
    }
}

// ---------------------------------------------------------------------------
extern "C" void kernel_launch(void* const* d_in, const int* in_sizes, int n_in,
                              void* d_out, int out_size, void* d_ws,
                              size_t ws_size, hipStream_t stream) {
    const float* positions = (const float*)d_in[0];
    const int* species = (const int*)d_in[1];
    const int* eidx = (const int*)d_in[2];
    const float* embedW = (const float*)d_in[3];
    const float* linupW0 = (const float*)d_in[4];
    const float* linupW1 = (const float*)d_in[5];
    const float* mlpW1 = (const float*)d_in[6];
    const float* mlpW2 = (const float*)d_in[7];
    const float* mlpW3 = (const float*)d_in[8];
    const float* linW0 = (const float*)d_in[9];
    const float* linW1 = (const float*)d_in[10];
    const float* prodW0 = (const float*)d_in[11];
    const float* prodW1 = (const float*)d_in[12];
    const float* plinW0 = (const float*)d_in[13];
    const float* plinW1 = (const float*)d_in[14];

    const int nn = in_sizes[0] / 3;   // 25000
    const int ne = in_sizes[2] / 2;   // 400000

    // workspace layout (floats): h0 | h1 | x0 | x1   (M aliases h: h dead
    // once lin_up produced x; node-update reads M row then overwrites it)
    float* h0 = (float*)d_ws;
    float* h1 = h0 + (size_t)nn * 64;
    float* x0 = h1 + (size_t)nn * 192;
    float* x1 = x0 + (size_t)nn * 64;

    const int gridN64 = (nn * 64 + 255) / 256;
    const int gridInit = (nn * 256 + 255) / 256;
    const int gridNode = (nn + 3) / 4;
    const int gridEdge = (ne + 63) / 64;

    // k_init fills h0 from the embedding AND zeroes h1 (no memset dispatch)
    k_init<<<gridInit, 256, 0, stream>>>(h0, h1, species, embedW, nn);

    for (int l = 0; l < 2; ++l) {
        // k_linup consumes h and zeroes it in place (fused accumulator
        // memset) -> no hipMemsetAsync dispatches in the loop.
        k_linup<<<gridNode, 256, 0, stream>>>(
            h0, h1, linupW0 + l * 4096, linupW1 + l * 4096, x0, x1, nn);
        k_edge<<<gridEdge, 320, 0, stream>>>(
            positions, eidx, x0, x1, mlpW1 + l * 512, mlpW2 + l * 4096,
            mlpW3 + l * 20480, h0, h1, ne);
        k_node<<<gridNode, 256, 0, stream>>>(
            h0, h1, species, linW0 + l * 4096, linW1 + l * 4096,
            prodW0 + l * 768, prodW1 + l * 512, plinW0 + l * 4096,
            plinW1 + l * 4096, nn);
    }
    k_out<<<gridN64, 256, 0, stream>>>(h0, h1, (float4*)d_out, nn);
}

// Round 10
// 1197.089 us; speedup vs baseline: 1.5520x; 1.1460x over previous
//
#include <hip/hip_runtime.h>
#include <math.h>

// Problem constants (C, HID, etc. are structural; N and E taken from in_sizes)
#define CDIM 64
#define NBES 8

#define SQRT3_F     1.7320508075688772f
#define INV_SQRT3_F 0.57735026918962576f
#define INV_SQRT2_F 0.70710678118654752f
#define INV_AVG_NN  0.0625f

__device__ __forceinline__ float silu(float x) {
    return x / (1.0f + expf(-x));
}

// ---------------------------------------------------------------------------
// init: h0[n,k] = node_embed_W[species[n], k]; h1 = 0 (replaces the h1 memset)
__global__ __launch_bounds__(256) void k_init(float* __restrict__ h0,
                                              float* __restrict__ h1,
                                              const int* __restrict__ species,
                                              const float* __restrict__ embedW,
                                              int nnodes) {
    int idx = blockIdx.x * 256 + threadIdx.x;
    int n64 = nnodes * 64;
    if (idx < n64) {
        int n = idx >> 6, k = idx & 63;
        h0[idx] = embedW[species[n] * 64 + k];
    } else if (idx < nnodes * 256) {
        h1[idx - n64] = 0.f;
    }
}

// ---------------------------------------------------------------------------
// lin_up: x0 = h0 @ W0 ; x1[d] = h1[d] @ W1   (h1 stored [N][3][C])
// Also ZEROES h0/h1 in place after consuming them (h aliases the scatter
// accumulators M0/M1 that k_edge atomically accumulates into) — this
// replaces the two per-layer hipMemsetAsync dispatches. Each row is read
// and zeroed by exactly one thread, and the zero-store targets the same
// address as the load, so ordering is guaranteed.
__global__ __launch_bounds__(256) void k_linup(float* __restrict__ h0,
                                               float* __restrict__ h1,
                                               const float* __restrict__ W0,
                                               const float* __restrict__ W1,
                                               float* __restrict__ x0,
                                               float* __restrict__ x1,
                                               int nnodes) {
    __shared__ float sh[4][4][64];
    const int w = threadIdx.x >> 6, k = threadIdx.x & 63;
    const int n = blockIdx.x * 4 + w;
    const bool valid = n < nnodes;
    float v0 = valid ? h0[n * 64 + k] : 0.f;
    float v1 = valid ? h1[n * 192 + k] : 0.f;
    float v2 = valid ? h1[n * 192 + 64 + k] : 0.f;
    float v3 = valid ? h1[n * 192 + 128 + k] : 0.f;
    sh[w][0][k] = v0; sh[w][1][k] = v1; sh[w][2][k] = v2; sh[w][3][k] = v3;
    if (valid) {  // zero the scatter accumulators (fused memset)
        h0[n * 64 + k] = 0.f;
        h1[n * 192 + k] = 0.f;
        h1[n * 192 + 64 + k] = 0.f;
        h1[n * 192 + 128 + k] = 0.f;
    }
    __syncthreads();
    float a0 = 0.f, a1 = 0.f, a2 = 0.f, a3 = 0.f;
    for (int c = 0; c < 64; ++c) {
        float w0 = W0[c * 64 + k], w1 = W1[c * 64 + k];
        a0 = fmaf(sh[w][0][c], w0, a0);
        a1 = fmaf(sh[w][1][c], w1, a1);
        a2 = fmaf(sh[w][2][c], w1, a2);
        a3 = fmaf(sh[w][3][c], w1, a3);
    }
    if (valid) {
        x0[n * 64 + k] = a0;
        x1[n * 192 + k] = a1;
        x1[n * 192 + 64 + k] = a2;
        x1[n * 192 + 128 + k] = a3;
    }
}

// ---------------------------------------------------------------------------
// LAYER-0 edge kernel. At layer 0, h1 == 0 => x1 == 0, so the CG tensor
// product degenerates: m0 = tpw0*xs0, m1 = tpw1*xs0*Y1 (paths 2,3,4 vanish).
// Consequences exploited here: tpw GEMM is 128 cols instead of 320 (40% of
// FLOPs), only x0 is gathered (1/4 of gather bytes), message math loses the
// cross product. Atomics unchanged. Layer 1 uses the frozen general kernel.
__global__ __launch_bounds__(320, 4) void k_edge0(
    const float* __restrict__ pos, const int* __restrict__ eidx,
    const float* __restrict__ x0,
    const float* __restrict__ W1, const float* __restrict__ W2,
    const float* __restrict__ W3,
    float* __restrict__ M0, float* __restrict__ M1, int nedges) {
    __shared__ __align__(16) float sFEAT[64][8];
    __shared__ float sY1[64][3];
    __shared__ int sSend[64];
    __shared__ int sRecv[64];
    __shared__ __align__(16) float sH2[64 * 68];
    __shared__ __align__(16) float sU0[4352];  // union: sH1T[64*68] | sTP[2][16][68]

    float* const sH1T = sU0;  // [k][edge], stride 68
    float* const sTP = sU0;   // [2][16][68]

    const int t = threadIdx.x;
    const int wv = t >> 6;

    // ---- P0: geometry + radial features (fp64 for accuracy), threads 0..63
    if (t < 64) {
        int e = blockIdx.x * 64 + t;
        int s = 0, r = 0;
        float y0 = 0.f, y1 = 0.f, y2 = 0.f;
        float feats[NBES];
#pragma unroll
        for (int b = 0; b < NBES; ++b) feats[b] = 0.f;
        if (e < nedges) {
            s = eidx[e];
            r = eidx[nedges + e];
            double dx = (double)pos[3 * s + 0] - (double)pos[3 * r + 0];
            double dy = (double)pos[3 * s + 1] - (double)pos[3 * r + 1];
            double dz = (double)pos[3 * s + 2] - (double)pos[3 * r + 2];
            double rr = sqrt(dx * dx + dy * dy + dz * dz);
            if (rr < 1e-6) rr = 1e-6;
            double inv = 1.0 / rr;
            y0 = (float)(1.7320508075688772 * dx * inv);
            y1 = (float)(1.7320508075688772 * dy * inv);
            y2 = (float)(1.7320508075688772 * dz * inv);
            double xx = rr * 0.2;  // r / R_MAX
            double f = 0.0;
            if (xx < 1.0) {
                double x2 = xx * xx, x3 = x2 * xx, x6 = x3 * x3;
                f = 1.0 - 28.0 * x6 + 48.0 * x6 * xx - 21.0 * x6 * x2;
            }
            double pref = 0.63245553203367587 * f * inv;  // sqrt(2/R_MAX)
#pragma unroll
            for (int b = 0; b < NBES; ++b) {
                double arg = (double)(b + 1) * 3.14159265358979324 * rr * 0.2;
                feats[b] = (float)(sin(arg) * pref);
            }
        }
        sSend[t] = s;
        sRecv[t] = r;
        sY1[t][0] = y0; sY1[t][1] = y1; sY1[t][2] = y2;
#pragma unroll
        for (int b = 0; b < NBES; ++b) sFEAT[t][b] = feats[b];
    }
    __syncthreads();

    // ---- P1: hid1 = silu(feat @ W1) -> sH1T[k][edge] (transposed, stride 68)
    if (t < 256) {
        const int j = t & 63;
        float w1c[NBES];
#pragma unroll
        for (int b = 0; b < NBES; ++b) w1c[b] = W1[b * 64 + j];
#pragma unroll
        for (int i = 0; i < 16; ++i) {
            int el = wv * 16 + i;
            const float4* fr = (const float4*)(&sFEAT[el][0]);
            float4 f0 = fr[0], f1 = fr[1];
            float acc = 0.f;
            acc = fmaf(f0.x, w1c[0], acc);
            acc = fmaf(f0.y, w1c[1], acc);
            acc = fmaf(f0.z, w1c[2], acc);
            acc = fmaf(f0.w, w1c[3], acc);
            acc = fmaf(f1.x, w1c[4], acc);
            acc = fmaf(f1.y, w1c[5], acc);
            acc = fmaf(f1.z, w1c[6], acc);
            acc = fmaf(f1.w, w1c[7], acc);
            sH1T[j * 68 + el] = silu(acc);
        }
    }
    __syncthreads();

    // ---- P2: hid2 = silu(hid1 @ W2), 4 edges x 4 cols per thread
    if (t < 256) {
        const int eg = t >> 4;
        const int j4 = (t & 15) * 4;
        float a00 = 0.f, a01 = 0.f, a02 = 0.f, a03 = 0.f;
        float a10 = 0.f, a11 = 0.f, a12 = 0.f, a13 = 0.f;
        float a20 = 0.f, a21 = 0.f, a22 = 0.f, a23 = 0.f;
        float a30 = 0.f, a31 = 0.f, a32 = 0.f, a33 = 0.f;
#pragma unroll 4
        for (int k = 0; k < 64; ++k) {
            float4 av = *(const float4*)&sH1T[k * 68 + 4 * eg];
            float4 wv4 = *(const float4*)&W2[k * 64 + j4];
            a00 = fmaf(av.x, wv4.x, a00); a01 = fmaf(av.x, wv4.y, a01);
            a02 = fmaf(av.x, wv4.z, a02); a03 = fmaf(av.x, wv4.w, a03);
            a10 = fmaf(av.y, wv4.x, a10); a11 = fmaf(av.y, wv4.y, a11);
            a12 = fmaf(av.y, wv4.z, a12); a13 = fmaf(av.y, wv4.w, a13);
            a20 = fmaf(av.z, wv4.x, a20); a21 = fmaf(av.z, wv4.y, a21);
            a22 = fmaf(av.z, wv4.z, a22); a23 = fmaf(av.z, wv4.w, a23);
            a30 = fmaf(av.w, wv4.x, a30); a31 = fmaf(av.w, wv4.y, a31);
            a32 = fmaf(av.w, wv4.z, a32); a33 = fmaf(av.w, wv4.w, a33);
        }
        *(float4*)&sH2[(4 * eg + 0) * 68 + j4] =
            make_float4(silu(a00), silu(a01), silu(a02), silu(a03));
        *(float4*)&sH2[(4 * eg + 1) * 68 + j4] =
            make_float4(silu(a10), silu(a11), silu(a12), silu(a13));
        *(float4*)&sH2[(4 * eg + 2) * 68 + j4] =
            make_float4(silu(a20), silu(a21), silu(a22), silu(a23));
        *(float4*)&sH2[(4 * eg + 3) * 68 + j4] =
            make_float4(silu(a30), silu(a31), silu(a32), silu(a33));
    }
    __syncthreads();  // sH2 ready; sH1T dead -> union free for sTP

    // ---- P3: GEMM over tpw paths 0,1 only (cols 0..127).
    // 256 threads: eb16 = t&15 (edge sub), cb8 = (t>>4)*8 (col block).
    // Thread owns edges {i*16+eb16 : i<4} x cols [cb8, cb8+8) -> acc[4][8].
    const int eb16 = t & 15;
    const int cb8 = (t >> 4) * 8;  // 0..120 for t<256
    float acc[4][8];
#pragma unroll
    for (int i = 0; i < 4; ++i)
#pragma unroll
        for (int j = 0; j < 8; ++j) acc[i][j] = 0.f;

    if (t < 256) {
#pragma unroll 1
        for (int kt = 0; kt < 16; ++kt) {
            float4 h[4];
#pragma unroll
            for (int i = 0; i < 4; ++i)
                h[i] = *(const float4*)&sH2[(i * 16 + eb16) * 68 + kt * 4];
#pragma unroll
            for (int kk = 0; kk < 4; ++kk) {
                const int k = kt * 4 + kk;
                float4 wa = *(const float4*)&W3[k * 320 + cb8];
                float4 wb = *(const float4*)&W3[k * 320 + cb8 + 4];
#pragma unroll
                for (int i = 0; i < 4; ++i) {
                    float hv = (kk == 0) ? h[i].x
                             : (kk == 1) ? h[i].y
                             : (kk == 2) ? h[i].z
                                         : h[i].w;
                    acc[i][0] = fmaf(hv, wa.x, acc[i][0]);
                    acc[i][1] = fmaf(hv, wa.y, acc[i][1]);
                    acc[i][2] = fmaf(hv, wa.z, acc[i][2]);
                    acc[i][3] = fmaf(hv, wa.w, acc[i][3]);
                    acc[i][4] = fmaf(hv, wb.x, acc[i][4]);
                    acc[i][5] = fmaf(hv, wb.y, acc[i][5]);
                    acc[i][6] = fmaf(hv, wb.z, acc[i][6]);
                    acc[i][7] = fmaf(hv, wb.w, acc[i][7]);
                }
            }
        }
    }

    // ---- P4: 4 message phases, 16 edges each. Phase g uses acc[g][*]
    // (edges g*16+eb16). Stage into sTP[p][el][ch], p = cb8>>6, c = cb8&63.
    const int p0 = cb8 >> 6;
    const int c0 = cb8 & 63;
#pragma unroll
    for (int g = 0; g < 4; ++g) {
        if (t < 256) {
            const int row = (p0 * 16 + eb16) * 68 + c0;
            *(float4*)&sTP[row] =
                make_float4(acc[g][0], acc[g][1], acc[g][2], acc[g][3]);
            *(float4*)&sTP[row + 4] =
                make_float4(acc[g][4], acc[g][5], acc[g][6], acc[g][7]);
        }
        __syncthreads();  // tpw staged
        // 16 edges x 64 channels = 1024 items over 320 threads
        for (int v = t; v < 1024; v += 320) {
            int i = v >> 6, cc = v & 63;
            int el = g * 16 + i;
            int s = sSend[el], r = sRecv[el];
            float X0 = x0[s * 64 + cc];
            float Yx = sY1[el][0], Yy = sY1[el][1], Yz = sY1[el][2];
            float t0 = sTP[(0 * 16 + i) * 68 + cc];
            float t1 = sTP[(1 * 16 + i) * 68 + cc];
            float m0 = t0 * X0;
            float m1 = t1 * X0 * INV_AVG_NN;
            atomicAdd(&M0[r * 64 + cc], m0 * INV_AVG_NN);
            atomicAdd(&M1[r * 192 + cc], m1 * Yx);
            atomicAdd(&M1[r * 192 + 64 + cc], m1 * Yy);
            atomicAdd(&M1[r * 192 + 128 + cc], m1 * Yz);
        }
        __syncthreads();  // sTP reads done before next phase overwrites it
    }
}

// ---------------------------------------------------------------------------
// Edge kernel: 64 edges per 320-thread block. BYTE-IDENTICAL to the round-6
// version (602 us, the session best). Nine rounds of evidence: this
// kernel's schedule quality is codegen-sensitive (r7/r8 perturbations cost
// 95-240 us at identical counters), so it is frozen. Structure:
// P0 geometry -> P1 hid1 (sH1T transposed) -> P2 hid2 (4x4 reg tile, W2
// from global) -> P3 barrier-free 8x8 GEMM (W3 from global, L2-hot) ->
// P4 4 message phases with atomic scatter.
__global__ __launch_bounds__(320, 4) void k_edge(
    const float* __restrict__ pos, const int* __restrict__ eidx,
    const float* __restrict__ x0, const float* __restrict__ x1,
    const float* __restrict__ W1, const float* __restrict__ W2,
    const float* __restrict__ W3,
    float* __restrict__ M0, float* __restrict__ M1, int nedges) {
    __shared__ __align__(16) float sFEAT[64][8];
    __shared__ float sY1[64][3];
    __shared__ int sSend[64];
    __shared__ int sRecv[64];
    __shared__ __align__(16) float sH2[64 * 68];  // pad 68: b128 rows, banks spread
    __shared__ __align__(16) float sU[5440];      // union: sH1T[64*68] | sTP[5*16*68]

    float* const sH1T = sU;  // [k][edge], stride 68
    float* const sTP = sU;   // [5][16][68]

    const int t = threadIdx.x;
    const int eb = t & 7;          // GEMM: edge sub-index (edges i*8+eb)
    const int cb8 = (t >> 3) * 8;  // GEMM: first owned tpw column (0..312)
    const int wv = t >> 6;         // wave index == path index of owned cols
    const int c0 = cb8 & 63;       // channel offset within path block

    // ---- P0: geometry + radial features (fp64 for accuracy), threads 0..63
    if (t < 64) {
        int e = blockIdx.x * 64 + t;
        int s = 0, r = 0;
        float y0 = 0.f, y1 = 0.f, y2 = 0.f;
        float feats[NBES];
#pragma unroll
        for (int b = 0; b < NBES; ++b) feats[b] = 0.f;
        if (e < nedges) {
            s = eidx[e];
            r = eidx[nedges + e];
            double dx = (double)pos[3 * s + 0] - (double)pos[3 * r + 0];
            double dy = (double)pos[3 * s + 1] - (double)pos[3 * r + 1];
            double dz = (double)pos[3 * s + 2] - (double)pos[3 * r + 2];
            double rr = sqrt(dx * dx + dy * dy + dz * dz);
            if (rr < 1e-6) rr = 1e-6;
            double inv = 1.0 / rr;
            y0 = (float)(1.7320508075688772 * dx * inv);
            y1 = (float)(1.7320508075688772 * dy * inv);
            y2 = (float)(1.7320508075688772 * dz * inv);
            double xx = rr * 0.2;  // r / R_MAX
            double f = 0.0;
            if (xx < 1.0) {
                double x2 = xx * xx, x3 = x2 * xx, x6 = x3 * x3;
                f = 1.0 - 28.0 * x6 + 48.0 * x6 * xx - 21.0 * x6 * x2;
            }
            double pref = 0.63245553203367587 * f * inv;  // sqrt(2/R_MAX)
#pragma unroll
            for (int b = 0; b < NBES; ++b) {
                double arg = (double)(b + 1) * 3.14159265358979324 * rr * 0.2;
                feats[b] = (float)(sin(arg) * pref);
            }
        }
        sSend[t] = s;
        sRecv[t] = r;
        sY1[t][0] = y0; sY1[t][1] = y1; sY1[t][2] = y2;
#pragma unroll
        for (int b = 0; b < NBES; ++b) sFEAT[t][b] = feats[b];
    }
    __syncthreads();

    // ---- P1: hid1 = silu(feat @ W1) -> sH1T[k][edge] (transposed, stride 68)
    if (t < 256) {
        const int j = t & 63;
        float w1c[NBES];
#pragma unroll
        for (int b = 0; b < NBES; ++b) w1c[b] = W1[b * 64 + j];
#pragma unroll
        for (int i = 0; i < 16; ++i) {
            int el = wv * 16 + i;
            const float4* fr = (const float4*)(&sFEAT[el][0]);  // broadcast reads
            float4 f0 = fr[0], f1 = fr[1];
            float acc = 0.f;
            acc = fmaf(f0.x, w1c[0], acc);
            acc = fmaf(f0.y, w1c[1], acc);
            acc = fmaf(f0.z, w1c[2], acc);
            acc = fmaf(f0.w, w1c[3], acc);
            acc = fmaf(f1.x, w1c[4], acc);
            acc = fmaf(f1.y, w1c[5], acc);
            acc = fmaf(f1.z, w1c[6], acc);
            acc = fmaf(f1.w, w1c[7], acc);
            sH1T[j * 68 + el] = silu(acc);
        }
    }
    __syncthreads();

    // ---- P2: hid2 = silu(hid1 @ W2), 4 edges x 4 cols per thread,
    // A from sH1T (b128), B from global W2 (L1-resident, 16KB).
    if (t < 256) {
        const int eg = t >> 4;         // edge group: edges 4*eg..+4
        const int j4 = (t & 15) * 4;   // col group: cols j4..j4+4
        float a00 = 0.f, a01 = 0.f, a02 = 0.f, a03 = 0.f;
        float a10 = 0.f, a11 = 0.f, a12 = 0.f, a13 = 0.f;
        float a20 = 0.f, a21 = 0.f, a22 = 0.f, a23 = 0.f;
        float a30 = 0.f, a31 = 0.f, a32 = 0.f, a33 = 0.f;
#pragma unroll 4
        for (int k = 0; k < 64; ++k) {
            float4 av = *(const float4*)&sH1T[k * 68 + 4 * eg];
            float4 wv4 = *(const float4*)&W2[k * 64 + j4];
            a00 = fmaf(av.x, wv4.x, a00); a01 = fmaf(av.x, wv4.y, a01);
            a02 = fmaf(av.x, wv4.z, a02); a03 = fmaf(av.x, wv4.w, a03);
            a10 = fmaf(av.y, wv4.x, a10); a11 = fmaf(av.y, wv4.y, a11);
            a12 = fmaf(av.y, wv4.z, a12); a13 = fmaf(av.y, wv4.w, a13);
            a20 = fmaf(av.z, wv4.x, a20); a21 = fmaf(av.z, wv4.y, a21);
            a22 = fmaf(av.z, wv4.z, a22); a23 = fmaf(av.z, wv4.w, a23);
            a30 = fmaf(av.w, wv4.x, a30); a31 = fmaf(av.w, wv4.y, a31);
            a32 = fmaf(av.w, wv4.z, a32); a33 = fmaf(av.w, wv4.w, a33);
        }
        *(float4*)&sH2[(4 * eg + 0) * 68 + j4] =
            make_float4(silu(a00), silu(a01), silu(a02), silu(a03));
        *(float4*)&sH2[(4 * eg + 1) * 68 + j4] =
            make_float4(silu(a10), silu(a11), silu(a12), silu(a13));
        *(float4*)&sH2[(4 * eg + 2) * 68 + j4] =
            make_float4(silu(a20), silu(a21), silu(a22), silu(a23));
        *(float4*)&sH2[(4 * eg + 3) * 68 + j4] =
            make_float4(silu(a30), silu(a31), silu(a32), silu(a33));
    }
    __syncthreads();  // sH2 ready; sH1T dead -> union free for sTP

    // ---- P3: barrier-free GEMM
    // acc[i][j] = sum_k sH2[i*8+eb][k] * W3[k][cb8+j]; W3 via VMEM (L2-hot)
    float acc[8][8];
#pragma unroll
    for (int i = 0; i < 8; ++i)
#pragma unroll
        for (int j = 0; j < 8; ++j) acc[i][j] = 0.f;

#pragma unroll 1
    for (int kt = 0; kt < 16; ++kt) {  // K-step 4
        float4 h[8];
#pragma unroll
        for (int i = 0; i < 8; ++i)
            h[i] = *(const float4*)&sH2[(i * 8 + eb) * 68 + kt * 4];
#pragma unroll
        for (int kk = 0; kk < 4; ++kk) {
            const int k = kt * 4 + kk;
            float4 wa = *(const float4*)&W3[k * 320 + cb8];
            float4 wb = *(const float4*)&W3[k * 320 + cb8 + 4];
#pragma unroll
            for (int i = 0; i < 8; ++i) {
                float hv = (kk == 0) ? h[i].x
                         : (kk == 1) ? h[i].y
                         : (kk == 2) ? h[i].z
                                     : h[i].w;
                acc[i][0] = fmaf(hv, wa.x, acc[i][0]);
                acc[i][1] = fmaf(hv, wa.y, acc[i][1]);
                acc[i][2] = fmaf(hv, wa.z, acc[i][2]);
                acc[i][3] = fmaf(hv, wa.w, acc[i][3]);
                acc[i][4] = fmaf(hv, wb.x, acc[i][4]);
                acc[i][5] = fmaf(hv, wb.y, acc[i][5]);
                acc[i][6] = fmaf(hv, wb.z, acc[i][6]);
                acc[i][7] = fmaf(hv, wb.w, acc[i][7]);
            }
        }
    }

    // ---- P4: 4 message phases, 16 edges each. Thread stages acc[2g][*]
    // (edge g*16+eb) and acc[2g+1][*] (edge g*16+8+eb) into sTP[p][el][ch].
#pragma unroll
    for (int g = 0; g < 4; ++g) {
        {
            const int rowA = (wv * 16 + eb) * 68 + c0;
            const int rowB = (wv * 16 + 8 + eb) * 68 + c0;
            *(float4*)&sTP[rowA] =
                make_float4(acc[2 * g][0], acc[2 * g][1], acc[2 * g][2], acc[2 * g][3]);
            *(float4*)&sTP[rowA + 4] =
                make_float4(acc[2 * g][4], acc[2 * g][5], acc[2 * g][6], acc[2 * g][7]);
            *(float4*)&sTP[rowB] =
                make_float4(acc[2 * g + 1][0], acc[2 * g + 1][1], acc[2 * g + 1][2], acc[2 * g + 1][3]);
            *(float4*)&sTP[rowB + 4] =
                make_float4(acc[2 * g + 1][4], acc[2 * g + 1][5], acc[2 * g + 1][6], acc[2 * g + 1][7]);
        }
        __syncthreads();  // tpw staged
        // 16 edges x 64 channels = 1024 items over 320 threads
        for (int v = t; v < 1024; v += 320) {
            int i = v >> 6, cc = v & 63;
            int el = g * 16 + i;
            int s = sSend[el], r = sRecv[el];
            float X0 = x0[s * 64 + cc];
            float Xx = x1[s * 192 + cc];
            float Xy = x1[s * 192 + 64 + cc];
            float Xz = x1[s * 192 + 128 + cc];
            float Yx = sY1[el][0], Yy = sY1[el][1], Yz = sY1[el][2];
            float t0 = sTP[(0 * 16 + i) * 68 + cc];
            float t1 = sTP[(1 * 16 + i) * 68 + cc];
            float t2 = sTP[(2 * 16 + i) * 68 + cc];
            float t3 = sTP[(3 * 16 + i) * 68 + cc];
            float t4 = sTP[(4 * 16 + i) * 68 + cc];
            float dotp = Xx * Yx + Xy * Yy + Xz * Yz;
            float m0 = t0 * X0 + t3 * (dotp * INV_SQRT3_F);
            float cx = Xy * Yz - Xz * Yy;
            float cy = Xz * Yx - Xx * Yz;
            float cz = Xx * Yy - Xy * Yx;
            float m1x = t1 * X0 * Yx + t2 * Xx + t4 * (cx * INV_SQRT2_F);
            float m1y = t1 * X0 * Yy + t2 * Xy + t4 * (cy * INV_SQRT2_F);
            float m1z = t1 * X0 * Yz + t2 * Xz + t4 * (cz * INV_SQRT2_F);
            atomicAdd(&M0[r * 64 + cc], m0 * INV_AVG_NN);
            atomicAdd(&M1[r * 192 + cc], m1x * INV_AVG_NN);
            atomicAdd(&M1[r * 192 + 64 + cc], m1y * INV_AVG_NN);
            atomicAdd(&M1[r * 192 + 128 + cc], m1z * INV_AVG_NN);
        }
        __syncthreads();  // sTP reads done before next phase overwrites it
    }
}

// ---------------------------------------------------------------------------
// Node update: h = prod_lin( product_basis( lin(M) ) ), in place over M
__global__ __launch_bounds__(256) void k_node(
    float* __restrict__ h0, float* __restrict__ h1,
    const int* __restrict__ species,
    const float* __restrict__ linW0, const float* __restrict__ linW1,
    const float* __restrict__ prodW0, const float* __restrict__ prodW1,
    const float* __restrict__ plinW0, const float* __restrict__ plinW1,
    int nnodes) {
    __shared__ float sh[4][4][64];
    const int w = threadIdx.x >> 6, k = threadIdx.x & 63;
    const int n = blockIdx.x * 4 + w;
    const bool valid = n < nnodes;
    float v0 = valid ? h0[n * 64 + k] : 0.f;
    float v1 = valid ? h1[n * 192 + k] : 0.f;
    float v2 = valid ? h1[n * 192 + 64 + k] : 0.f;
    float v3 = valid ? h1[n * 192 + 128 + k] : 0.f;
    sh[w][0][k] = v0; sh[w][1][k] = v1; sh[w][2][k] = v2; sh[w][3][k] = v3;
    __syncthreads();
    float a0 = 0.f, a1 = 0.f, a2 = 0.f, a3 = 0.f;
    for (int c = 0; c < 64; ++c) {
        float w0 = linW0[c * 64 + k], w1 = linW1[c * 64 + k];
        a0 = fmaf(sh[w][0][c], w0, a0);
        a1 = fmaf(sh[w][1][c], w1, a1);
        a2 = fmaf(sh[w][2][c], w1, a2);
        a3 = fmaf(sh[w][3][c], w1, a3);
    }
    // product basis (elementwise in channel)
    int sp = valid ? species[n] : 0;
    float p00 = prodW0[sp * 192 + k];
    float p01 = prodW0[sp * 192 + 64 + k];
    float p02 = prodW0[sp * 192 + 128 + k];
    float p10 = prodW1[sp * 128 + k];
    float p11 = prodW1[sp * 128 + 64 + k];
    float nsq = a1 * a1 + a2 * a2 + a3 * a3;
    float b0 = p00 * a0 + p01 * (a0 * a0) + p02 * (nsq * INV_SQRT3_F);
    float b1x = p10 * a1 + p11 * (a0 * a1);
    float b1y = p10 * a2 + p11 * (a0 * a2);
    float b1z = p10 * a3 + p11 * (a0 * a3);
    __syncthreads();
    sh[w][0][k] = b0; sh[w][1][k] = b1x; sh[w][2][k] = b1y; sh[w][3][k] = b1z;
    __syncthreads();
    a0 = a1 = a2 = a3 = 0.f;
    for (int c = 0; c < 64; ++c) {
        float w0 = plinW0[c * 64 + k], w1 = plinW1[c * 64 + k];
        a0 = fmaf(sh[w][0][c], w0, a0);
        a1 = fmaf(sh[w][1][c], w1, a1);
        a2 = fmaf(sh[w][2][c], w1, a2);
        a3 = fmaf(sh[w][3][c], w1, a3);
    }
    if (valid) {
        h0[n * 64 + k] = a0;
        h1[n * 192 + k] = a1;
        h1[n * 192 + 64 + k] = a2;
        h1[n * 192 + 128 + k] = a3;
    }
}

// ---------------------------------------------------------------------------
// Output: [N, C, 4] = concat(h0, h1_x, h1_y, h1_z) along last dim
__global__ __launch_bounds__(256) void k_out(const float* __restrict__ h0,
                                             const float* __restrict__ h1,
                                             float4* __restrict__ out,
                                             int nnodes) {
    int idx = blockIdx.x * 256 + threadIdx.x;
    if (idx < nnodes * 64) {
        int n = idx >> 6, c = idx & 63;
        float4 o;
        o.x = h0[idx];
        o.y = h1[n * 192 + c];
        o.z = h1[n * 192 + 64 + c];
        o.w = h1[n * 192 + 128 + c];
        out[idx] = o;
    }
}

// ---------------------------------------------------------------------------
extern "C" void kernel_launch(void* const* d_in, const int* in_sizes, int n_in,
                              void* d_out, int out_size, void* d_ws,
                              size_t ws_size, hipStream_t stream) {
    const float* positions = (const float*)d_in[0];
    const int* species = (const int*)d_in[1];
    const int* eidx = (const int*)d_in[2];
    const float* embedW = (const float*)d_in[3];
    const float* linupW0 = (const float*)d_in[4];
    const float* linupW1 = (const float*)d_in[5];
    const float* mlpW1 = (const float*)d_in[6];
    const float* mlpW2 = (const float*)d_in[7];
    const float* mlpW3 = (const float*)d_in[8];
    const float* linW0 = (const float*)d_in[9];
    const float* linW1 = (const float*)d_in[10];
    const float* prodW0 = (const float*)d_in[11];
    const float* prodW1 = (const float*)d_in[12];
    const float* plinW0 = (const float*)d_in[13];
    const float* plinW1 = (const float*)d_in[14];

    const int nn = in_sizes[0] / 3;   // 25000
    const int ne = in_sizes[2] / 2;   // 400000

    // workspace layout (floats): h0 | h1 | x0 | x1   (M aliases h: h dead
    // once lin_up produced x; node-update reads M row then overwrites it)
    float* h0 = (float*)d_ws;
    float* h1 = h0 + (size_t)nn * 64;
    float* x0 = h1 + (size_t)nn * 192;
    float* x1 = x0 + (size_t)nn * 64;

    const int gridN64 = (nn * 64 + 255) / 256;
    const int gridInit = (nn * 256 + 255) / 256;
    const int gridNode = (nn + 3) / 4;
    const int gridEdge = (ne + 63) / 64;

    // k_init fills h0 from the embedding AND zeroes h1 (no memset dispatch)
    k_init<<<gridInit, 256, 0, stream>>>(h0, h1, species, embedW, nn);

    // ---- layer 0: h1==0 -> x1==0 -> specialized edge kernel (paths 0,1)
    k_linup<<<gridNode, 256, 0, stream>>>(
        h0, h1, linupW0, linupW1, x0, x1, nn);
    k_edge0<<<gridEdge, 320, 0, stream>>>(
        positions, eidx, x0, mlpW1, mlpW2, mlpW3, h0, h1, ne);
    k_node<<<gridNode, 256, 0, stream>>>(
        h0, h1, species, linW0, linW1, prodW0, prodW1, plinW0, plinW1, nn);

    // ---- layer 1: general path (frozen r6 kernel)
    k_linup<<<gridNode, 256, 0, stream>>>(
        h0, h1, linupW0 + 4096, linupW1 + 4096, x0, x1, nn);
    k_edge<<<gridEdge, 320, 0, stream>>>(
        positions, eidx, x0, x1, mlpW1 + 512, mlpW2 + 4096,
        mlpW3 + 20480, h0, h1, ne);
    k_node<<<gridNode, 256, 0, stream>>>(
        h0, h1, species, linW0 + 4096, linW1 + 4096,
        prodW0 + 768, prodW1 + 512, plinW0 + 4096, plinW1 + 4096, nn);

    k_out<<<gridN64, 256, 0, stream>>>(h0, h1, (float4*)d_out, nn);
}

// Round 11
// 1170.177 us; speedup vs baseline: 1.5877x; 1.0230x over previous
//
#include <hip/hip_runtime.h>
#include <math.h>

// Problem constants (C, HID, etc. are structural; N and E taken from in_sizes)
#define CDIM 64
#define NBES 8

#define SQRT3_F     1.7320508075688772f
#define INV_SQRT3_F 0.57735026918962576f
#define INV_SQRT2_F 0.70710678118654752f
#define INV_AVG_NN  0.0625f

__device__ __forceinline__ float silu(float x) {
    return x / (1.0f + expf(-x));
}

// ---------------------------------------------------------------------------
// Layer-0 front end, fully fused: x0 = embed[species] @ W0 computed straight
// from the embedding table (wave-uniform row: all 64 lanes of a wave handle
// one node), h0/h1 zeroed as scatter accumulators. x1 is NOT computed -- at
// layer 0 h1==0 => x1==0 and k_edge0 never reads it. Replaces k_init +
// layer-0 k_linup (one dispatch and ~45 MB of h traffic removed).
__global__ __launch_bounds__(256) void k_lin0(
    float* __restrict__ h0, float* __restrict__ h1,
    const int* __restrict__ species, const float* __restrict__ embedW,
    const float* __restrict__ W0, float* __restrict__ x0, int nnodes) {
    const int w = threadIdx.x >> 6, k = threadIdx.x & 63;
    const int n = blockIdx.x * 4 + w;
    if (n >= nnodes) return;
    const float* er = embedW + species[n] * 64;  // wave-uniform
    float a0 = 0.f;
    for (int c = 0; c < 64; ++c) a0 = fmaf(er[c], W0[c * 64 + k], a0);
    x0[n * 64 + k] = a0;
    h0[n * 64 + k] = 0.f;
    h1[n * 192 + k] = 0.f;
    h1[n * 192 + 64 + k] = 0.f;
    h1[n * 192 + 128 + k] = 0.f;
}

// ---------------------------------------------------------------------------
// LAYER-0 edge kernel. At layer 0, h1 == 0 => x1 == 0, so the CG tensor
// product degenerates: m0 = tpw0*xs0, m1 = tpw1*xs0*Y1 (paths 2,3,4 vanish).
// Consequences exploited here: tpw GEMM is 128 cols instead of 320 (40% of
// FLOPs), only x0 is gathered (1/4 of gather bytes), message math loses the
// cross product. Atomics unchanged. Layer 1 uses the frozen general kernel.
// BYTE-IDENTICAL to round-10 (session-verified ~430 us).
__global__ __launch_bounds__(320, 4) void k_edge0(
    const float* __restrict__ pos, const int* __restrict__ eidx,
    const float* __restrict__ x0,
    const float* __restrict__ W1, const float* __restrict__ W2,
    const float* __restrict__ W3,
    float* __restrict__ M0, float* __restrict__ M1, int nedges) {
    __shared__ __align__(16) float sFEAT[64][8];
    __shared__ float sY1[64][3];
    __shared__ int sSend[64];
    __shared__ int sRecv[64];
    __shared__ __align__(16) float sH2[64 * 68];
    __shared__ __align__(16) float sU0[4352];  // union: sH1T[64*68] | sTP[2][16][68]

    float* const sH1T = sU0;  // [k][edge], stride 68
    float* const sTP = sU0;   // [2][16][68]

    const int t = threadIdx.x;
    const int wv = t >> 6;

    // ---- P0: geometry + radial features (fp64 for accuracy), threads 0..63
    if (t < 64) {
        int e = blockIdx.x * 64 + t;
        int s = 0, r = 0;
        float y0 = 0.f, y1 = 0.f, y2 = 0.f;
        float feats[NBES];
#pragma unroll
        for (int b = 0; b < NBES; ++b) feats[b] = 0.f;
        if (e < nedges) {
            s = eidx[e];
            r = eidx[nedges + e];
            double dx = (double)pos[3 * s + 0] - (double)pos[3 * r + 0];
            double dy = (double)pos[3 * s + 1] - (double)pos[3 * r + 1];
            double dz = (double)pos[3 * s + 2] - (double)pos[3 * r + 2];
            double rr = sqrt(dx * dx + dy * dy + dz * dz);
            if (rr < 1e-6) rr = 1e-6;
            double inv = 1.0 / rr;
            y0 = (float)(1.7320508075688772 * dx * inv);
            y1 = (float)(1.7320508075688772 * dy * inv);
            y2 = (float)(1.7320508075688772 * dz * inv);
            double xx = rr * 0.2;  // r / R_MAX
            double f = 0.0;
            if (xx < 1.0) {
                double x2 = xx * xx, x3 = x2 * xx, x6 = x3 * x3;
                f = 1.0 - 28.0 * x6 + 48.0 * x6 * xx - 21.0 * x6 * x2;
            }
            double pref = 0.63245553203367587 * f * inv;  // sqrt(2/R_MAX)
#pragma unroll
            for (int b = 0; b < NBES; ++b) {
                double arg = (double)(b + 1) * 3.14159265358979324 * rr * 0.2;
                feats[b] = (float)(sin(arg) * pref);
            }
        }
        sSend[t] = s;
        sRecv[t] = r;
        sY1[t][0] = y0; sY1[t][1] = y1; sY1[t][2] = y2;
#pragma unroll
        for (int b = 0; b < NBES; ++b) sFEAT[t][b] = feats[b];
    }
    __syncthreads();

    // ---- P1: hid1 = silu(feat @ W1) -> sH1T[k][edge] (transposed, stride 68)
    if (t < 256) {
        const int j = t & 63;
        float w1c[NBES];
#pragma unroll
        for (int b = 0; b < NBES; ++b) w1c[b] = W1[b * 64 + j];
#pragma unroll
        for (int i = 0; i < 16; ++i) {
            int el = wv * 16 + i;
            const float4* fr = (const float4*)(&sFEAT[el][0]);
            float4 f0 = fr[0], f1 = fr[1];
            float acc = 0.f;
            acc = fmaf(f0.x, w1c[0], acc);
            acc = fmaf(f0.y, w1c[1], acc);
            acc = fmaf(f0.z, w1c[2], acc);
            acc = fmaf(f0.w, w1c[3], acc);
            acc = fmaf(f1.x, w1c[4], acc);
            acc = fmaf(f1.y, w1c[5], acc);
            acc = fmaf(f1.z, w1c[6], acc);
            acc = fmaf(f1.w, w1c[7], acc);
            sH1T[j * 68 + el] = silu(acc);
        }
    }
    __syncthreads();

    // ---- P2: hid2 = silu(hid1 @ W2), 4 edges x 4 cols per thread
    if (t < 256) {
        const int eg = t >> 4;
        const int j4 = (t & 15) * 4;
        float a00 = 0.f, a01 = 0.f, a02 = 0.f, a03 = 0.f;
        float a10 = 0.f, a11 = 0.f, a12 = 0.f, a13 = 0.f;
        float a20 = 0.f, a21 = 0.f, a22 = 0.f, a23 = 0.f;
        float a30 = 0.f, a31 = 0.f, a32 = 0.f, a33 = 0.f;
#pragma unroll 4
        for (int k = 0; k < 64; ++k) {
            float4 av = *(const float4*)&sH1T[k * 68 + 4 * eg];
            float4 wv4 = *(const float4*)&W2[k * 64 + j4];
            a00 = fmaf(av.x, wv4.x, a00); a01 = fmaf(av.x, wv4.y, a01);
            a02 = fmaf(av.x, wv4.z, a02); a03 = fmaf(av.x, wv4.w, a03);
            a10 = fmaf(av.y, wv4.x, a10); a11 = fmaf(av.y, wv4.y, a11);
            a12 = fmaf(av.y, wv4.z, a12); a13 = fmaf(av.y, wv4.w, a13);
            a20 = fmaf(av.z, wv4.x, a20); a21 = fmaf(av.z, wv4.y, a21);
            a22 = fmaf(av.z, wv4.z, a22); a23 = fmaf(av.z, wv4.w, a23);
            a30 = fmaf(av.w, wv4.x, a30); a31 = fmaf(av.w, wv4.y, a31);
            a32 = fmaf(av.w, wv4.z, a32); a33 = fmaf(av.w, wv4.w, a33);
        }
        *(float4*)&sH2[(4 * eg + 0) * 68 + j4] =
            make_float4(silu(a00), silu(a01), silu(a02), silu(a03));
        *(float4*)&sH2[(4 * eg + 1) * 68 + j4] =
            make_float4(silu(a10), silu(a11), silu(a12), silu(a13));
        *(float4*)&sH2[(4 * eg + 2) * 68 + j4] =
            make_float4(silu(a20), silu(a21), silu(a22), silu(a23));
        *(float4*)&sH2[(4 * eg + 3) * 68 + j4] =
            make_float4(silu(a30), silu(a31), silu(a32), silu(a33));
    }
    __syncthreads();  // sH2 ready; sH1T dead -> union free for sTP

    // ---- P3: GEMM over tpw paths 0,1 only (cols 0..127).
    const int eb16 = t & 15;
    const int cb8 = (t >> 4) * 8;  // 0..120 for t<256
    float acc[4][8];
#pragma unroll
    for (int i = 0; i < 4; ++i)
#pragma unroll
        for (int j = 0; j < 8; ++j) acc[i][j] = 0.f;

    if (t < 256) {
#pragma unroll 1
        for (int kt = 0; kt < 16; ++kt) {
            float4 h[4];
#pragma unroll
            for (int i = 0; i < 4; ++i)
                h[i] = *(const float4*)&sH2[(i * 16 + eb16) * 68 + kt * 4];
#pragma unroll
            for (int kk = 0; kk < 4; ++kk) {
                const int k = kt * 4 + kk;
                float4 wa = *(const float4*)&W3[k * 320 + cb8];
                float4 wb = *(const float4*)&W3[k * 320 + cb8 + 4];
#pragma unroll
                for (int i = 0; i < 4; ++i) {
                    float hv = (kk == 0) ? h[i].x
                             : (kk == 1) ? h[i].y
                             : (kk == 2) ? h[i].z
                                         : h[i].w;
                    acc[i][0] = fmaf(hv, wa.x, acc[i][0]);
                    acc[i][1] = fmaf(hv, wa.y, acc[i][1]);
                    acc[i][2] = fmaf(hv, wa.z, acc[i][2]);
                    acc[i][3] = fmaf(hv, wa.w, acc[i][3]);
                    acc[i][4] = fmaf(hv, wb.x, acc[i][4]);
                    acc[i][5] = fmaf(hv, wb.y, acc[i][5]);
                    acc[i][6] = fmaf(hv, wb.z, acc[i][6]);
                    acc[i][7] = fmaf(hv, wb.w, acc[i][7]);
                }
            }
        }
    }

    // ---- P4: 4 message phases, 16 edges each.
    const int p0 = cb8 >> 6;
    const int c0 = cb8 & 63;
#pragma unroll
    for (int g = 0; g < 4; ++g) {
        if (t < 256) {
            const int row = (p0 * 16 + eb16) * 68 + c0;
            *(float4*)&sTP[row] =
                make_float4(acc[g][0], acc[g][1], acc[g][2], acc[g][3]);
            *(float4*)&sTP[row + 4] =
                make_float4(acc[g][4], acc[g][5], acc[g][6], acc[g][7]);
        }
        __syncthreads();  // tpw staged
        for (int v = t; v < 1024; v += 320) {
            int i = v >> 6, cc = v & 63;
            int el = g * 16 + i;
            int s = sSend[el], r = sRecv[el];
            float X0 = x0[s * 64 + cc];
            float Yx = sY1[el][0], Yy = sY1[el][1], Yz = sY1[el][2];
            float t0 = sTP[(0 * 16 + i) * 68 + cc];
            float t1 = sTP[(1 * 16 + i) * 68 + cc];
            float m0 = t0 * X0;
            float m1 = t1 * X0 * INV_AVG_NN;
            atomicAdd(&M0[r * 64 + cc], m0 * INV_AVG_NN);
            atomicAdd(&M1[r * 192 + cc], m1 * Yx);
            atomicAdd(&M1[r * 192 + 64 + cc], m1 * Yy);
            atomicAdd(&M1[r * 192 + 128 + cc], m1 * Yz);
        }
        __syncthreads();  // sTP reads done before next phase overwrites it
    }
}

// ---------------------------------------------------------------------------
// Edge kernel: 64 edges per 320-thread block. BYTE-IDENTICAL to the round-6
// version (602 us, the session best; r9/r10 confirmed binary stability
// across TU changes). Frozen: r7/r8 perturbations cost 95-240 us.
__global__ __launch_bounds__(320, 4) void k_edge(
    const float* __restrict__ pos, const int* __restrict__ eidx,
    const float* __restrict__ x0, const float* __restrict__ x1,
    const float* __restrict__ W1, const float* __restrict__ W2,
    const float* __restrict__ W3,
    float* __restrict__ M0, float* __restrict__ M1, int nedges) {
    __shared__ __align__(16) float sFEAT[64][8];
    __shared__ float sY1[64][3];
    __shared__ int sSend[64];
    __shared__ int sRecv[64];
    __shared__ __align__(16) float sH2[64 * 68];  // pad 68: b128 rows, banks spread
    __shared__ __align__(16) float sU[5440];      // union: sH1T[64*68] | sTP[5*16*68]

    float* const sH1T = sU;  // [k][edge], stride 68
    float* const sTP = sU;   // [5][16][68]

    const int t = threadIdx.x;
    const int eb = t & 7;          // GEMM: edge sub-index (edges i*8+eb)
    const int cb8 = (t >> 3) * 8;  // GEMM: first owned tpw column (0..312)
    const int wv = t >> 6;         // wave index == path index of owned cols
    const int c0 = cb8 & 63;       // channel offset within path block

    // ---- P0: geometry + radial features (fp64 for accuracy), threads 0..63
    if (t < 64) {
        int e = blockIdx.x * 64 + t;
        int s = 0, r = 0;
        float y0 = 0.f, y1 = 0.f, y2 = 0.f;
        float feats[NBES];
#pragma unroll
        for (int b = 0; b < NBES; ++b) feats[b] = 0.f;
        if (e < nedges) {
            s = eidx[e];
            r = eidx[nedges + e];
            double dx = (double)pos[3 * s + 0] - (double)pos[3 * r + 0];
            double dy = (double)pos[3 * s + 1] - (double)pos[3 * r + 1];
            double dz = (double)pos[3 * s + 2] - (double)pos[3 * r + 2];
            double rr = sqrt(dx * dx + dy * dy + dz * dz);
            if (rr < 1e-6) rr = 1e-6;
            double inv = 1.0 / rr;
            y0 = (float)(1.7320508075688772 * dx * inv);
            y1 = (float)(1.7320508075688772 * dy * inv);
            y2 = (float)(1.7320508075688772 * dz * inv);
            double xx = rr * 0.2;  // r / R_MAX
            double f = 0.0;
            if (xx < 1.0) {
                double x2 = xx * xx, x3 = x2 * xx, x6 = x3 * x3;
                f = 1.0 - 28.0 * x6 + 48.0 * x6 * xx - 21.0 * x6 * x2;
            }
            double pref = 0.63245553203367587 * f * inv;  // sqrt(2/R_MAX)
#pragma unroll
            for (int b = 0; b < NBES; ++b) {
                double arg = (double)(b + 1) * 3.14159265358979324 * rr * 0.2;
                feats[b] = (float)(sin(arg) * pref);
            }
        }
        sSend[t] = s;
        sRecv[t] = r;
        sY1[t][0] = y0; sY1[t][1] = y1; sY1[t][2] = y2;
#pragma unroll
        for (int b = 0; b < NBES; ++b) sFEAT[t][b] = feats[b];
    }
    __syncthreads();

    // ---- P1: hid1 = silu(feat @ W1) -> sH1T[k][edge] (transposed, stride 68)
    if (t < 256) {
        const int j = t & 63;
        float w1c[NBES];
#pragma unroll
        for (int b = 0; b < NBES; ++b) w1c[b] = W1[b * 64 + j];
#pragma unroll
        for (int i = 0; i < 16; ++i) {
            int el = wv * 16 + i;
            const float4* fr = (const float4*)(&sFEAT[el][0]);  // broadcast reads
            float4 f0 = fr[0], f1 = fr[1];
            float acc = 0.f;
            acc = fmaf(f0.x, w1c[0], acc);
            acc = fmaf(f0.y, w1c[1], acc);
            acc = fmaf(f0.z, w1c[2], acc);
            acc = fmaf(f0.w, w1c[3], acc);
            acc = fmaf(f1.x, w1c[4], acc);
            acc = fmaf(f1.y, w1c[5], acc);
            acc = fmaf(f1.z, w1c[6], acc);
            acc = fmaf(f1.w, w1c[7], acc);
            sH1T[j * 68 + el] = silu(acc);
        }
    }
    __syncthreads();

    // ---- P2: hid2 = silu(hid1 @ W2), 4 edges x 4 cols per thread,
    // A from sH1T (b128), B from global W2 (L1-resident, 16KB).
    if (t < 256) {
        const int eg = t >> 4;         // edge group: edges 4*eg..+4
        const int j4 = (t & 15) * 4;   // col group: cols j4..j4+4
        float a00 = 0.f, a01 = 0.f, a02 = 0.f, a03 = 0.f;
        float a10 = 0.f, a11 = 0.f, a12 = 0.f, a13 = 0.f;
        float a20 = 0.f, a21 = 0.f, a22 = 0.f, a23 = 0.f;
        float a30 = 0.f, a31 = 0.f, a32 = 0.f, a33 = 0.f;
#pragma unroll 4
        for (int k = 0; k < 64; ++k) {
            float4 av = *(const float4*)&sH1T[k * 68 + 4 * eg];
            float4 wv4 = *(const float4*)&W2[k * 64 + j4];
            a00 = fmaf(av.x, wv4.x, a00); a01 = fmaf(av.x, wv4.y, a01);
            a02 = fmaf(av.x, wv4.z, a02); a03 = fmaf(av.x, wv4.w, a03);
            a10 = fmaf(av.y, wv4.x, a10); a11 = fmaf(av.y, wv4.y, a11);
            a12 = fmaf(av.y, wv4.z, a12); a13 = fmaf(av.y, wv4.w, a13);
            a20 = fmaf(av.z, wv4.x, a20); a21 = fmaf(av.z, wv4.y, a21);
            a22 = fmaf(av.z, wv4.z, a22); a23 = fmaf(av.z, wv4.w, a23);
            a30 = fmaf(av.w, wv4.x, a30); a31 = fmaf(av.w, wv4.y, a31);
            a32 = fmaf(av.w, wv4.z, a32); a33 = fmaf(av.w, wv4.w, a33);
        }
        *(float4*)&sH2[(4 * eg + 0) * 68 + j4] =
            make_float4(silu(a00), silu(a01), silu(a02), silu(a03));
        *(float4*)&sH2[(4 * eg + 1) * 68 + j4] =
            make_float4(silu(a10), silu(a11), silu(a12), silu(a13));
        *(float4*)&sH2[(4 * eg + 2) * 68 + j4] =
            make_float4(silu(a20), silu(a21), silu(a22), silu(a23));
        *(float4*)&sH2[(4 * eg + 3) * 68 + j4] =
            make_float4(silu(a30), silu(a31), silu(a32), silu(a33));
    }
    __syncthreads();  // sH2 ready; sH1T dead -> union free for sTP

    // ---- P3: barrier-free GEMM
    // acc[i][j] = sum_k sH2[i*8+eb][k] * W3[k][cb8+j]; W3 via VMEM (L2-hot)
    float acc[8][8];
#pragma unroll
    for (int i = 0; i < 8; ++i)
#pragma unroll
        for (int j = 0; j < 8; ++j) acc[i][j] = 0.f;

#pragma unroll 1
    for (int kt = 0; kt < 16; ++kt) {  // K-step 4
        float4 h[8];
#pragma unroll
        for (int i = 0; i < 8; ++i)
            h[i] = *(const float4*)&sH2[(i * 8 + eb) * 68 + kt * 4];
#pragma unroll
        for (int kk = 0; kk < 4; ++kk) {
            const int k = kt * 4 + kk;
            float4 wa = *(const float4*)&W3[k * 320 + cb8];
            float4 wb = *(const float4*)&W3[k * 320 + cb8 + 4];
#pragma unroll
            for (int i = 0; i < 8; ++i) {
                float hv = (kk == 0) ? h[i].x
                         : (kk == 1) ? h[i].y
                         : (kk == 2) ? h[i].z
                                     : h[i].w;
                acc[i][0] = fmaf(hv, wa.x, acc[i][0]);
                acc[i][1] = fmaf(hv, wa.y, acc[i][1]);
                acc[i][2] = fmaf(hv, wa.z, acc[i][2]);
                acc[i][3] = fmaf(hv, wa.w, acc[i][3]);
                acc[i][4] = fmaf(hv, wb.x, acc[i][4]);
                acc[i][5] = fmaf(hv, wb.y, acc[i][5]);
                acc[i][6] = fmaf(hv, wb.z, acc[i][6]);
                acc[i][7] = fmaf(hv, wb.w, acc[i][7]);
            }
        }
    }

    // ---- P4: 4 message phases, 16 edges each. Thread stages acc[2g][*]
    // (edge g*16+eb) and acc[2g+1][*] (edge g*16+8+eb) into sTP[p][el][ch].
#pragma unroll
    for (int g = 0; g < 4; ++g) {
        {
            const int rowA = (wv * 16 + eb) * 68 + c0;
            const int rowB = (wv * 16 + 8 + eb) * 68 + c0;
            *(float4*)&sTP[rowA] =
                make_float4(acc[2 * g][0], acc[2 * g][1], acc[2 * g][2], acc[2 * g][3]);
            *(float4*)&sTP[rowA + 4] =
                make_float4(acc[2 * g][4], acc[2 * g][5], acc[2 * g][6], acc[2 * g][7]);
            *(float4*)&sTP[rowB] =
                make_float4(acc[2 * g + 1][0], acc[2 * g + 1][1], acc[2 * g + 1][2], acc[2 * g + 1][3]);
            *(float4*)&sTP[rowB + 4] =
                make_float4(acc[2 * g + 1][4], acc[2 * g + 1][5], acc[2 * g + 1][6], acc[2 * g + 1][7]);
        }
        __syncthreads();  // tpw staged
        // 16 edges x 64 channels = 1024 items over 320 threads
        for (int v = t; v < 1024; v += 320) {
            int i = v >> 6, cc = v & 63;
            int el = g * 16 + i;
            int s = sSend[el], r = sRecv[el];
            float X0 = x0[s * 64 + cc];
            float Xx = x1[s * 192 + cc];
            float Xy = x1[s * 192 + 64 + cc];
            float Xz = x1[s * 192 + 128 + cc];
            float Yx = sY1[el][0], Yy = sY1[el][1], Yz = sY1[el][2];
            float t0 = sTP[(0 * 16 + i) * 68 + cc];
            float t1 = sTP[(1 * 16 + i) * 68 + cc];
            float t2 = sTP[(2 * 16 + i) * 68 + cc];
            float t3 = sTP[(3 * 16 + i) * 68 + cc];
            float t4 = sTP[(4 * 16 + i) * 68 + cc];
            float dotp = Xx * Yx + Xy * Yy + Xz * Yz;
            float m0 = t0 * X0 + t3 * (dotp * INV_SQRT3_F);
            float cx = Xy * Yz - Xz * Yy;
            float cy = Xz * Yx - Xx * Yz;
            float cz = Xx * Yy - Xy * Yx;
            float m1x = t1 * X0 * Yx + t2 * Xx + t4 * (cx * INV_SQRT2_F);
            float m1y = t1 * X0 * Yy + t2 * Xy + t4 * (cy * INV_SQRT2_F);
            float m1z = t1 * X0 * Yz + t2 * Xz + t4 * (cz * INV_SQRT2_F);
            atomicAdd(&M0[r * 64 + cc], m0 * INV_AVG_NN);
            atomicAdd(&M1[r * 192 + cc], m1x * INV_AVG_NN);
            atomicAdd(&M1[r * 192 + 64 + cc], m1y * INV_AVG_NN);
            atomicAdd(&M1[r * 192 + 128 + cc], m1z * INV_AVG_NN);
        }
        __syncthreads();  // sTP reads done before next phase overwrites it
    }
}

// ---------------------------------------------------------------------------
// Fused layer-0 node update + layer-1 lin_up. Reads M (in h0/h1), zeroes
// h0/h1 in place (layer-1 scatter accumulators), chains four LDS-staged
// GEMM stages: lin -> product basis -> prod_lin -> lin_up, writing x0/x1.
// The intermediate h never touches HBM (saves 51 MB round trip + dispatch).
__global__ __launch_bounds__(256) void k_nodelin(
    float* __restrict__ h0, float* __restrict__ h1,
    const int* __restrict__ species,
    const float* __restrict__ linW0, const float* __restrict__ linW1,
    const float* __restrict__ prodW0, const float* __restrict__ prodW1,
    const float* __restrict__ plinW0, const float* __restrict__ plinW1,
    const float* __restrict__ lupW0, const float* __restrict__ lupW1,
    float* __restrict__ x0, float* __restrict__ x1, int nnodes) {
    __shared__ float sh[4][4][64];
    const int w = threadIdx.x >> 6, k = threadIdx.x & 63;
    const int n = blockIdx.x * 4 + w;
    const bool valid = n < nnodes;
    float v0 = valid ? h0[n * 64 + k] : 0.f;
    float v1 = valid ? h1[n * 192 + k] : 0.f;
    float v2 = valid ? h1[n * 192 + 64 + k] : 0.f;
    float v3 = valid ? h1[n * 192 + 128 + k] : 0.f;
    sh[w][0][k] = v0; sh[w][1][k] = v1; sh[w][2][k] = v2; sh[w][3][k] = v3;
    if (valid) {  // zero scatter accumulators for layer 1
        h0[n * 64 + k] = 0.f;
        h1[n * 192 + k] = 0.f;
        h1[n * 192 + 64 + k] = 0.f;
        h1[n * 192 + 128 + k] = 0.f;
    }
    __syncthreads();
    // stage 1: lin
    float a0 = 0.f, a1 = 0.f, a2 = 0.f, a3 = 0.f;
    for (int c = 0; c < 64; ++c) {
        float w0 = linW0[c * 64 + k], w1 = linW1[c * 64 + k];
        a0 = fmaf(sh[w][0][c], w0, a0);
        a1 = fmaf(sh[w][1][c], w1, a1);
        a2 = fmaf(sh[w][2][c], w1, a2);
        a3 = fmaf(sh[w][3][c], w1, a3);
    }
    // product basis (elementwise in channel)
    int sp = valid ? species[n] : 0;
    float p00 = prodW0[sp * 192 + k];
    float p01 = prodW0[sp * 192 + 64 + k];
    float p02 = prodW0[sp * 192 + 128 + k];
    float p10 = prodW1[sp * 128 + k];
    float p11 = prodW1[sp * 128 + 64 + k];
    float nsq = a1 * a1 + a2 * a2 + a3 * a3;
    float b0 = p00 * a0 + p01 * (a0 * a0) + p02 * (nsq * INV_SQRT3_F);
    float b1x = p10 * a1 + p11 * (a0 * a1);
    float b1y = p10 * a2 + p11 * (a0 * a2);
    float b1z = p10 * a3 + p11 * (a0 * a3);
    __syncthreads();
    sh[w][0][k] = b0; sh[w][1][k] = b1x; sh[w][2][k] = b1y; sh[w][3][k] = b1z;
    __syncthreads();
    // stage 2: prod_lin -> new h (registers only)
    a0 = a1 = a2 = a3 = 0.f;
    for (int c = 0; c < 64; ++c) {
        float w0 = plinW0[c * 64 + k], w1 = plinW1[c * 64 + k];
        a0 = fmaf(sh[w][0][c], w0, a0);
        a1 = fmaf(sh[w][1][c], w1, a1);
        a2 = fmaf(sh[w][2][c], w1, a2);
        a3 = fmaf(sh[w][3][c], w1, a3);
    }
    __syncthreads();
    sh[w][0][k] = a0; sh[w][1][k] = a1; sh[w][2][k] = a2; sh[w][3][k] = a3;
    __syncthreads();
    // stage 3: layer-1 lin_up
    a0 = a1 = a2 = a3 = 0.f;
    for (int c = 0; c < 64; ++c) {
        float w0 = lupW0[c * 64 + k], w1 = lupW1[c * 64 + k];
        a0 = fmaf(sh[w][0][c], w0, a0);
        a1 = fmaf(sh[w][1][c], w1, a1);
        a2 = fmaf(sh[w][2][c], w1, a2);
        a3 = fmaf(sh[w][3][c], w1, a3);
    }
    if (valid) {
        x0[n * 64 + k] = a0;
        x1[n * 192 + k] = a1;
        x1[n * 192 + 64 + k] = a2;
        x1[n * 192 + 128 + k] = a3;
    }
}

// ---------------------------------------------------------------------------
// Fused layer-1 node update + output: reads M, computes final h, writes the
// [N, C, 4] float4 output directly (final h never touches HBM).
__global__ __launch_bounds__(256) void k_nodeout(
    const float* __restrict__ h0, const float* __restrict__ h1,
    const int* __restrict__ species,
    const float* __restrict__ linW0, const float* __restrict__ linW1,
    const float* __restrict__ prodW0, const float* __restrict__ prodW1,
    const float* __restrict__ plinW0, const float* __restrict__ plinW1,
    float4* __restrict__ out, int nnodes) {
    __shared__ float sh[4][4][64];
    const int w = threadIdx.x >> 6, k = threadIdx.x & 63;
    const int n = blockIdx.x * 4 + w;
    const bool valid = n < nnodes;
    float v0 = valid ? h0[n * 64 + k] : 0.f;
    float v1 = valid ? h1[n * 192 + k] : 0.f;
    float v2 = valid ? h1[n * 192 + 64 + k] : 0.f;
    float v3 = valid ? h1[n * 192 + 128 + k] : 0.f;
    sh[w][0][k] = v0; sh[w][1][k] = v1; sh[w][2][k] = v2; sh[w][3][k] = v3;
    __syncthreads();
    float a0 = 0.f, a1 = 0.f, a2 = 0.f, a3 = 0.f;
    for (int c = 0; c < 64; ++c) {
        float w0 = linW0[c * 64 + k], w1 = linW1[c * 64 + k];
        a0 = fmaf(sh[w][0][c], w0, a0);
        a1 = fmaf(sh[w][1][c], w1, a1);
        a2 = fmaf(sh[w][2][c], w1, a2);
        a3 = fmaf(sh[w][3][c], w1, a3);
    }
    int sp = valid ? species[n] : 0;
    float p00 = prodW0[sp * 192 + k];
    float p01 = prodW0[sp * 192 + 64 + k];
    float p02 = prodW0[sp * 192 + 128 + k];
    float p10 = prodW1[sp * 128 + k];
    float p11 = prodW1[sp * 128 + 64 + k];
    float nsq = a1 * a1 + a2 * a2 + a3 * a3;
    float b0 = p00 * a0 + p01 * (a0 * a0) + p02 * (nsq * INV_SQRT3_F);
    float b1x = p10 * a1 + p11 * (a0 * a1);
    float b1y = p10 * a2 + p11 * (a0 * a2);
    float b1z = p10 * a3 + p11 * (a0 * a3);
    __syncthreads();
    sh[w][0][k] = b0; sh[w][1][k] = b1x; sh[w][2][k] = b1y; sh[w][3][k] = b1z;
    __syncthreads();
    a0 = a1 = a2 = a3 = 0.f;
    for (int c = 0; c < 64; ++c) {
        float w0 = plinW0[c * 64 + k], w1 = plinW1[c * 64 + k];
        a0 = fmaf(sh[w][0][c], w0, a0);
        a1 = fmaf(sh[w][1][c], w1, a1);
        a2 = fmaf(sh[w][2][c], w1, a2);
        a3 = fmaf(sh[w][3][c], w1, a3);
    }
    if (valid) out[n * 64 + k] = make_float4(a0, a1, a2, a3);
}

// ---------------------------------------------------------------------------
extern "C" void kernel_launch(void* const* d_in, const int* in_sizes, int n_in,
                              void* d_out, int out_size, void* d_ws,
                              size_t ws_size, hipStream_t stream) {
    const float* positions = (const float*)d_in[0];
    const int* species = (const int*)d_in[1];
    const int* eidx = (const int*)d_in[2];
    const float* embedW = (const float*)d_in[3];
    const float* linupW0 = (const float*)d_in[4];
    const float* linupW1 = (const float*)d_in[5];
    const float* mlpW1 = (const float*)d_in[6];
    const float* mlpW2 = (const float*)d_in[7];
    const float* mlpW3 = (const float*)d_in[8];
    const float* linW0 = (const float*)d_in[9];
    const float* linW1 = (const float*)d_in[10];
    const float* prodW0 = (const float*)d_in[11];
    const float* prodW1 = (const float*)d_in[12];
    const float* plinW0 = (const float*)d_in[13];
    const float* plinW1 = (const float*)d_in[14];

    const int nn = in_sizes[0] / 3;   // 25000
    const int ne = in_sizes[2] / 2;   // 400000

    // workspace layout (floats): h0 | h1 | x0 | x1   (h aliases the scatter
    // accumulators M0/M1)
    float* h0 = (float*)d_ws;
    float* h1 = h0 + (size_t)nn * 64;
    float* x0 = h1 + (size_t)nn * 192;
    float* x1 = x0 + (size_t)nn * 64;

    const int gridNode = (nn + 3) / 4;
    const int gridEdge = (ne + 63) / 64;

    // ---- layer 0: x0 straight from embedding (x1==0, not computed);
    // h0/h1 zeroed as accumulators. One dispatch replaces k_init+k_linup.
    k_lin0<<<gridNode, 256, 0, stream>>>(
        h0, h1, species, embedW, linupW0, x0, nn);
    k_edge0<<<gridEdge, 320, 0, stream>>>(
        positions, eidx, x0, mlpW1, mlpW2, mlpW3, h0, h1, ne);

    // ---- layer-0 node update fused with layer-1 lin_up (+ accumulator zero)
    k_nodelin<<<gridNode, 256, 0, stream>>>(
        h0, h1, species, linW0, linW1, prodW0, prodW1, plinW0, plinW1,
        linupW0 + 4096, linupW1 + 4096, x0, x1, nn);

    // ---- layer 1: frozen general edge kernel
    k_edge<<<gridEdge, 320, 0, stream>>>(
        positions, eidx, x0, x1, mlpW1 + 512, mlpW2 + 4096,
        mlpW3 + 20480, h0, h1, ne);

    // ---- layer-1 node update fused with output write
    k_nodeout<<<gridNode, 256, 0, stream>>>(
        h0, h1, species, linW0 + 4096, linW1 + 4096,
        prodW0 + 768, prodW1 + 512, plinW0 + 4096, plinW1 + 4096,
        (float4*)d_out, nn);
}